// Round 11
// baseline (3997.940 us; speedup 1.0000x reference)
//
#include <hip/hip_runtime.h>
#include <stdint.h>

// BiLSTM-CRF on gfx950 — fp32 (validated absmax 0.0). R17: cascade
// hi4 -> hi2 -> lo. R16 closed the 1024-thr path (allocator never grants
// >64 regs there). hi2 (512 thr, 2 waves/EU, 176 pinned) = 6.1 us/step,
// latency-limited: unroll-2 streamed loop keeps only ~4 loads in flight ->
// 92 GB/s/CU effective. hi4 = hi2 + (a) streamed loop unroll 4 (2x in-flight
// loads -> ~115-130 GB/s) + (b) QL 8->9 LDS quads (147.5 KB, register-
// neutral, stream 34->33 quads). FP chain identical (q ascending, same
// acc0/acc1 split) -> bitwise-same h. Probe-gated; hi2/lo fallbacks proven.

#define T_ 256
#define B_ 64
#define EPAD 304
#define KTAG 20
#define TB_ (T_ * B_)

// hi partitions (global k-quads 0..63, q ascending)
#define QR2 22                  // quads resident per gate-row (176 pinned, proven)
#define QL2A 8                  // hi2: quads in LDS (128 KiB)
#define QS2A 34                 // hi2: streamed
#define QL4 9                   // hi4: quads in LDS (144 KiB)
#define QS4 33                  // hi4: streamed

// lo (R8) partition
#define KR_LO 64
#define KLQ_LO 3
#define NQS_LO 45
#define WLDS_OFF_LO (2 * KR_LO * 1024)                    // 131072 floats
#define WSTR_OFF_LO (WLDS_OFF_LO + 2 * KLQ_LO * 1024 * 4) // 155648 floats

__device__ __forceinline__ float rlane(float v, int l) {
  return __int_as_float(__builtin_amdgcn_readlane(__float_as_int(v), l));
}

// ---------------- prep ----------------

__global__ void prep_embed(const int* __restrict__ x, const float* __restrict__ emb,
                           float* __restrict__ xsA) {
  int r = blockIdx.x;
  int tok = x[r];
  const float* src = emb + (size_t)tok * 300;
  for (int e = threadIdx.x; e < EPAD; e += 64)
    xsA[(size_t)r * EPAD + e] = (e < 300) ? src[e] : 0.f;
}

__global__ void prep_b0t(const float* __restrict__ Wih0, float* __restrict__ B0t) {
  int idx = blockIdx.x * 256 + threadIdx.x;
  if (idx >= 2048 * EPAD) return;
  int n = idx / EPAD, k = idx % EPAD;
  B0t[idx] = (k < 300) ? Wih0[(size_t)n * 300 + k] : 0.f;
}

__global__ void prep_bot64(const float* __restrict__ Wout, float* __restrict__ Bot,
                           const float* __restrict__ bout, float* __restrict__ biaso) {
  int idx = blockIdx.x * 256 + threadIdx.x;   // 64*512
  int n = idx >> 9, k = idx & 511;
  Bot[idx] = (n < KTAG) ? Wout[(size_t)n * 512 + k] : 0.f;
  if (idx < 64) biaso[idx] = (idx < KTAG) ? bout[idx] : 0.f;
}

// hi layout: whhU[d][q=k/4][gate][j][e]  (quad-major; lane j reads 16B at j*16)
__global__ void prep_whh4(const float* __restrict__ Whh, float* __restrict__ whhU) {
  int idx = blockIdx.x * 256 + threadIdx.x;   // 524288
  int d = idx >> 18, rem = idx & 262143, row = rem >> 8, k = rem & 255;
  float v = Whh[(size_t)d * 262144 + (size_t)row * 256 + k];
  int gt = row >> 8, j = row & 255;
  int q = k >> 2, e = k & 3;
  whhU[((((size_t)d * 64 + q) * 4 + gt) * 256 + j) * 4 + e] = v;
}

// lo layout (R8): thread tg owns row (tg&3)*256 + (tg>>2)
__global__ void prep_whh2(const float* __restrict__ Whh, float* __restrict__ whhL) {
  int idx = blockIdx.x * 256 + threadIdx.x;   // 524288
  int d = idx >> 18, rem = idx & 262143, k = rem >> 10, tg = rem & 1023;
  int row = (tg & 3) * 256 + (tg >> 2);
  float v = Whh[(size_t)d * 262144 + (size_t)row * 256 + k];
  if (k < KR_LO) {
    whhL[(size_t)(d * KR_LO + k) * 1024 + tg] = v;
  } else if (k < KR_LO + 12) {
    int kk = k - KR_LO, q = kk >> 2, e = kk & 3;
    whhL[WLDS_OFF_LO + (size_t)((d * KLQ_LO + q) * 1024 + tg) * 4 + e] = v;
  } else {
    int kk = k - KR_LO - 12, q = kk >> 2, e = kk & 3;
    whhL[WSTR_OFF_LO + (size_t)((d * NQS_LO + q) * 1024 + tg) * 4 + e] = v;
  }
}

// ---------------- fp32 GEMM: C[M,N] = A[M,K] * Bt[N,K]^T + bias ----------------
__global__ __launch_bounds__(256) void gemm_f32(
    const float* __restrict__ A, int lda, const float* __restrict__ Bt, int ldb,
    float* __restrict__ C, int ldc, const float* __restrict__ bias,
    int ntn, int K) {
  const int tm = blockIdx.x / ntn, tn = blockIdx.x % ntn;
  const int m0 = tm * 64, n0 = tn * 64;
  __shared__ __align__(16) float As[16][64];
  __shared__ __align__(16) float Bs[16][64];
  const int tid = threadIdx.x;
  const int mm = tid >> 2, kq = (tid & 3) * 4;
  const int tx = tid & 15, ty = tid >> 4;
  float acc[4][4] = {};
  for (int k0 = 0; k0 < K; k0 += 16) {
    float4 av = *(const float4*)&A[(size_t)(m0 + mm) * lda + k0 + kq];
    float4 bv = *(const float4*)&Bt[(size_t)(n0 + mm) * ldb + k0 + kq];
    __syncthreads();                       // guard prev-iter LDS reads
    As[kq + 0][mm] = av.x; As[kq + 1][mm] = av.y;
    As[kq + 2][mm] = av.z; As[kq + 3][mm] = av.w;
    Bs[kq + 0][mm] = bv.x; Bs[kq + 1][mm] = bv.y;
    Bs[kq + 2][mm] = bv.z; Bs[kq + 3][mm] = bv.w;
    __syncthreads();
#pragma unroll
    for (int kk = 0; kk < 16; ++kk) {
      float4 a4 = *(const float4*)&As[kk][ty * 4];
      float4 b4 = *(const float4*)&Bs[kk][tx * 4];
      acc[0][0] += a4.x * b4.x; acc[0][1] += a4.x * b4.y;
      acc[0][2] += a4.x * b4.z; acc[0][3] += a4.x * b4.w;
      acc[1][0] += a4.y * b4.x; acc[1][1] += a4.y * b4.y;
      acc[1][2] += a4.y * b4.z; acc[1][3] += a4.y * b4.w;
      acc[2][0] += a4.z * b4.x; acc[2][1] += a4.z * b4.y;
      acc[2][2] += a4.z * b4.z; acc[2][3] += a4.z * b4.w;
      acc[3][0] += a4.w * b4.x; acc[3][1] += a4.w * b4.y;
      acc[3][2] += a4.w * b4.z; acc[3][3] += a4.w * b4.w;
    }
  }
#pragma unroll
  for (int i = 0; i < 4; ++i)
#pragma unroll
    for (int j = 0; j < 4; ++j)
      C[(size_t)(m0 + ty * 4 + i) * ldc + n0 + tx * 4 + j] =
          acc[i][j] + bias[n0 + tx * 4 + j];
}

// ---------------- hi4 LSTM: hi2 + unroll-4 stream + QL=9 ----------
__global__ __attribute__((amdgpu_flat_work_group_size(512, 512),
                          amdgpu_waves_per_eu(2, 2)))
void lstm_rec_hi4(const float* __restrict__ xg, const float* __restrict__ whhU,
                  float* __restrict__ out, const int* __restrict__ lens) {
  const int wg = blockIdx.x, d = wg & 1, b = wg >> 1;
  const int len = lens[b];
  const int tg = threadIdx.x;
  const int j = tg & 255, gp = tg >> 8;    // gp 0: gates i,f ; gp 1: gates g,o
  const int g0 = gp * 2;
  const int l = tg & 63;
  const float* wb = whhU + (size_t)d * 64 * 4096;

  float4 wA[QR2], wB[QR2];
#pragma unroll
  for (int q = 0; q < QR2; ++q) {
    wA[q] = *(const float4*)(wb + ((size_t)(q * 4 + g0) * 256 + j) * 4);
    wB[q] = *(const float4*)(wb + ((size_t)(q * 4 + g0 + 1) * 256 + j) * 4);
  }
#pragma unroll
  for (int q = 0; q < QR2; ++q) {
    asm volatile("" : "+v"(wA[q].x), "+v"(wA[q].y), "+v"(wA[q].z), "+v"(wA[q].w));
    asm volatile("" : "+v"(wB[q].x), "+v"(wB[q].y), "+v"(wB[q].z), "+v"(wB[q].w));
  }

  __shared__ __align__(16) float4 wlds[QL4][4][256];  // 144 KiB
  __shared__ __align__(16) float hsd[2][256];
  __shared__ __align__(8) float2 exch[256];
  for (int i = tg; i < QL4 * 4 * 256; i += 512) {
    int q3 = i >> 10, g = (i >> 8) & 3, jj = i & 255;
    wlds[q3][g][jj] =
        *(const float4*)(wb + ((size_t)((QR2 + q3) * 4 + g) * 256 + jj) * 4);
  }
  if (tg < 256) hsd[0][tg] = 0.f;
  float c = 0.f;
  __syncthreads();

  for (int s = 0; s < len; ++s) {
    const int t = d ? (len - 1 - s) : s;
    const int rp = t * B_ + b;
    const size_t xb = (size_t)rp * 2048 + d * 1024 + (size_t)g0 * 256 + j;
    float xv0 = xg[xb];
    float xv1 = xg[xb + 256];
    float4 hv = *(const float4*)&hsd[s & 1][l * 4];

    float aA0 = 0.f, aA1 = 0.f, aB0 = 0.f, aB1 = 0.f;
#pragma unroll
    for (int q = 0; q < QR2; ++q) {        // k ascending = validated FP chain
      float b0 = rlane(hv.x, q), b1 = rlane(hv.y, q);
      float b2 = rlane(hv.z, q), b3 = rlane(hv.w, q);
      aA0 += wA[q].x * b0 + wA[q].y * b1;  aA1 += wA[q].z * b2 + wA[q].w * b3;
      aB0 += wB[q].x * b0 + wB[q].y * b1;  aB1 += wB[q].z * b2 + wB[q].w * b3;
    }
#pragma unroll
    for (int q3 = 0; q3 < QL4; ++q3) {
      int q = QR2 + q3;
      float b0 = rlane(hv.x, q), b1 = rlane(hv.y, q);
      float b2 = rlane(hv.z, q), b3 = rlane(hv.w, q);
      float4 wa = wlds[q3][g0][j], wbq = wlds[q3][g0 + 1][j];
      aA0 += wa.x * b0 + wa.y * b1;   aA1 += wa.z * b2 + wa.w * b3;
      aB0 += wbq.x * b0 + wbq.y * b1; aB1 += wbq.z * b2 + wbq.w * b3;
    }
#pragma unroll 4
    for (int qs = 0; qs < QS4; ++qs) {     // deeper unroll: ~8 loads in flight
      int q = QR2 + QL4 + qs;
      float4 wa = *(const float4*)(wb + ((size_t)(q * 4 + g0) * 256 + j) * 4);
      float4 wbq = *(const float4*)(wb + ((size_t)(q * 4 + g0 + 1) * 256 + j) * 4);
      float b0 = rlane(hv.x, q), b1 = rlane(hv.y, q);
      float b2 = rlane(hv.z, q), b3 = rlane(hv.w, q);
      aA0 += wa.x * b0 + wa.y * b1;   aA1 += wa.z * b2 + wa.w * b3;
      aB0 += wbq.x * b0 + wbq.y * b1; aB1 += wbq.z * b2 + wbq.w * b3;
    }

    float aA = aA0 + aA1 + xv0;            // gp0: i ; gp1: g
    float aB = aB0 + aB1 + xv1;            // gp0: f ; gp1: o
    if (gp == 1) exch[j] = make_float2(aA, aB);
    __syncthreads();
    if (gp == 0) {
      float2 go = exch[j];
      float si = 1.f / (1.f + expf(-aA));  // i
      float sf = 1.f / (1.f + expf(-aB));  // f
      float so = 1.f / (1.f + expf(-go.y));// o
      c = sf * c + si * tanhf(go.x);       // g
      float h = so * tanhf(c);
      hsd[(s + 1) & 1][j] = h;
      out[(size_t)rp * 512 + d * 256 + j] = h;
    }
    __syncthreads();
  }
  if (gp == 0)                              // pack_padded: padded outputs zero
    for (int t = len; t < T_; ++t)
      out[(size_t)(t * B_ + b) * 512 + d * 256 + j] = 0.f;
}

// ---------------- hi2 LSTM: R13 verbatim (proven 1551-1571 us) ----------
__global__ __attribute__((amdgpu_flat_work_group_size(512, 512),
                          amdgpu_waves_per_eu(2, 2)))
void lstm_rec_hi2(const float* __restrict__ xg, const float* __restrict__ whhU,
                  float* __restrict__ out, const int* __restrict__ lens) {
  const int wg = blockIdx.x, d = wg & 1, b = wg >> 1;
  const int len = lens[b];
  const int tg = threadIdx.x;
  const int j = tg & 255, gp = tg >> 8;
  const int g0 = gp * 2;
  const int l = tg & 63;
  const float* wb = whhU + (size_t)d * 64 * 4096;

  float4 wA[QR2], wB[QR2];
#pragma unroll
  for (int q = 0; q < QR2; ++q) {
    wA[q] = *(const float4*)(wb + ((size_t)(q * 4 + g0) * 256 + j) * 4);
    wB[q] = *(const float4*)(wb + ((size_t)(q * 4 + g0 + 1) * 256 + j) * 4);
  }
#pragma unroll
  for (int q = 0; q < QR2; ++q) {
    asm volatile("" : "+v"(wA[q].x), "+v"(wA[q].y), "+v"(wA[q].z), "+v"(wA[q].w));
    asm volatile("" : "+v"(wB[q].x), "+v"(wB[q].y), "+v"(wB[q].z), "+v"(wB[q].w));
  }

  __shared__ __align__(16) float4 wlds[QL2A][4][256];  // 128 KiB
  __shared__ __align__(16) float hsd[2][256];
  __shared__ __align__(8) float2 exch[256];
  for (int i = tg; i < QL2A * 4 * 256; i += 512) {
    int q3 = i >> 10, g = (i >> 8) & 3, jj = i & 255;
    wlds[q3][g][jj] =
        *(const float4*)(wb + ((size_t)((QR2 + q3) * 4 + g) * 256 + jj) * 4);
  }
  if (tg < 256) hsd[0][tg] = 0.f;
  float c = 0.f;
  __syncthreads();

  for (int s = 0; s < len; ++s) {
    const int t = d ? (len - 1 - s) : s;
    const int rp = t * B_ + b;
    const size_t xb = (size_t)rp * 2048 + d * 1024 + (size_t)g0 * 256 + j;
    float xv0 = xg[xb];
    float xv1 = xg[xb + 256];
    float4 hv = *(const float4*)&hsd[s & 1][l * 4];

    float aA0 = 0.f, aA1 = 0.f, aB0 = 0.f, aB1 = 0.f;
#pragma unroll
    for (int q = 0; q < QR2; ++q) {
      float b0 = rlane(hv.x, q), b1 = rlane(hv.y, q);
      float b2 = rlane(hv.z, q), b3 = rlane(hv.w, q);
      aA0 += wA[q].x * b0 + wA[q].y * b1;  aA1 += wA[q].z * b2 + wA[q].w * b3;
      aB0 += wB[q].x * b0 + wB[q].y * b1;  aB1 += wB[q].z * b2 + wB[q].w * b3;
    }
#pragma unroll
    for (int q3 = 0; q3 < QL2A; ++q3) {
      int q = QR2 + q3;
      float b0 = rlane(hv.x, q), b1 = rlane(hv.y, q);
      float b2 = rlane(hv.z, q), b3 = rlane(hv.w, q);
      float4 wa = wlds[q3][g0][j], wbq = wlds[q3][g0 + 1][j];
      aA0 += wa.x * b0 + wa.y * b1;   aA1 += wa.z * b2 + wa.w * b3;
      aB0 += wbq.x * b0 + wbq.y * b1; aB1 += wbq.z * b2 + wbq.w * b3;
    }
#pragma unroll 2
    for (int qs = 0; qs < QS2A; ++qs) {
      int q = QR2 + QL2A + qs;
      float4 wa = *(const float4*)(wb + ((size_t)(q * 4 + g0) * 256 + j) * 4);
      float4 wbq = *(const float4*)(wb + ((size_t)(q * 4 + g0 + 1) * 256 + j) * 4);
      float b0 = rlane(hv.x, q), b1 = rlane(hv.y, q);
      float b2 = rlane(hv.z, q), b3 = rlane(hv.w, q);
      aA0 += wa.x * b0 + wa.y * b1;   aA1 += wa.z * b2 + wa.w * b3;
      aB0 += wbq.x * b0 + wbq.y * b1; aB1 += wbq.z * b2 + wbq.w * b3;
    }

    float aA = aA0 + aA1 + xv0;
    float aB = aB0 + aB1 + xv1;
    if (gp == 1) exch[j] = make_float2(aA, aB);
    __syncthreads();
    if (gp == 0) {
      float2 go = exch[j];
      float si = 1.f / (1.f + expf(-aA));
      float sf = 1.f / (1.f + expf(-aB));
      float so = 1.f / (1.f + expf(-go.y));
      c = sf * c + si * tanhf(go.x);
      float h = so * tanhf(c);
      hsd[(s + 1) & 1][j] = h;
      out[(size_t)rp * 512 + d * 256 + j] = h;
    }
    __syncthreads();
  }
  if (gp == 0)
    for (int t = len; t < T_; ++t)
      out[(size_t)(t * B_ + b) * 512 + d * 256 + j] = 0.f;
}

// ---------------- lo LSTM: verbatim R8 (proven 1963 us, absmax 0.0) ----------
__global__ __launch_bounds__(1024, 4) void lstm_rec_lo(
    const float* __restrict__ xg, const float* __restrict__ whhL,
    float* __restrict__ out, const int* __restrict__ lens) {
  const int wg = blockIdx.x, dir = wg & 1, b = wg >> 1;
  const int len = lens[b];
  const int tg = threadIdx.x;
  const int j = tg >> 2, gt = tg & 3;
  const int row = gt * 256 + j;

  float wres[KR_LO];
#pragma unroll
  for (int k = 0; k < KR_LO; ++k)
    wres[k] = whhL[(size_t)(dir * KR_LO + k) * 1024 + tg];

  __shared__ __align__(16) float4 wlds[KLQ_LO][1024];
  __shared__ __align__(16) float hsd[2][256];
#pragma unroll
  for (int q = 0; q < KLQ_LO; ++q)
    wlds[q][tg] = *(const float4*)&whhL[WLDS_OFF_LO + (size_t)((dir * KLQ_LO + q) * 1024 + tg) * 4];
  if (tg < 256) hsd[0][tg] = 0.f;
  float c = 0.f;
  __syncthreads();

  const float* sp = whhL + WSTR_OFF_LO + (size_t)dir * NQS_LO * 4096 + (size_t)tg * 4;
  const int lane = tg & 63, qb = lane & ~3;

  for (int s = 0; s < len; ++s) {
    const int t = dir ? (len - 1 - s) : s;
    const int rp = t * B_ + b;
    float xv = xg[(size_t)rp * 2048 + dir * 1024 + row];
    float4 hv = *(const float4*)&hsd[s & 1][lane * 4];

    float acc0 = 0.f, acc1 = 0.f;
#pragma unroll
    for (int q = 0; q < KR_LO / 4; ++q) {
      float b0 = rlane(hv.x, q), b1 = rlane(hv.y, q);
      float b2 = rlane(hv.z, q), b3 = rlane(hv.w, q);
      acc0 += wres[4 * q + 0] * b0 + wres[4 * q + 1] * b1;
      acc1 += wres[4 * q + 2] * b2 + wres[4 * q + 3] * b3;
    }
#pragma unroll
    for (int q3 = 0; q3 < KLQ_LO; ++q3) {
      int q = KR_LO / 4 + q3;
      float4 wl = wlds[q3][tg];
      float b0 = rlane(hv.x, q), b1 = rlane(hv.y, q);
      float b2 = rlane(hv.z, q), b3 = rlane(hv.w, q);
      acc0 += wl.x * b0 + wl.y * b1;
      acc1 += wl.z * b2 + wl.w * b3;
    }
#pragma unroll 5
    for (int qq = 0; qq < NQS_LO; ++qq) {
      int q = KR_LO / 4 + KLQ_LO + qq;
      float4 wv = *(const float4*)(sp + (size_t)qq * 4096);
      float b0 = rlane(hv.x, q), b1 = rlane(hv.y, q);
      float b2 = rlane(hv.z, q), b3 = rlane(hv.w, q);
      acc0 += wv.x * b0 + wv.y * b1;
      acc1 += wv.z * b2 + wv.w * b3;
    }

    float a = acc0 + acc1 + xv;
    float v1 = __shfl(a, qb | 1);
    float v2 = __shfl(a, qb | 2);
    float v3 = __shfl(a, qb | 3);
    if (gt == 0) {
      float si = 1.f / (1.f + expf(-a));
      float sf = 1.f / (1.f + expf(-v1));
      float so = 1.f / (1.f + expf(-v3));
      c = sf * c + si * tanhf(v2);
      float h = so * tanhf(c);
      hsd[(s + 1) & 1][j] = h;
      out[(size_t)rp * 512 + dir * 256 + j] = h;
    }
    __syncthreads();
  }
  for (int t = len; t < T_; ++t)
    if (gt == 0) out[(size_t)(t * B_ + b) * 512 + dir * 256 + j] = 0.f;
}

// ---------------- Viterbi (one wave per batch; ref fp-op order) ----------------
__global__ __launch_bounds__(64) void viterbi(
    const float* __restrict__ emis, const float* __restrict__ trans,
    const float* __restrict__ startv, const float* __restrict__ endv,
    const int* __restrict__ lens, int* __restrict__ outp) {
  int b = blockIdx.x, lane = threadIdx.x;
  __shared__ float tr[KTAG * KTAG];
  __shared__ float fin[KTAG];
  __shared__ unsigned char hist[T_ * KTAG];
  for (int i = lane; i < KTAG * KTAG; i += 64) tr[i] = trans[i];
  int len = lens[b];
  float score = (lane < KTAG) ? startv[lane] + emis[(size_t)b * 64 + lane] : -3e38f;
  __syncthreads();
  for (int t = 1; t < len; ++t) {
    float e = (lane < KTAG) ? emis[(size_t)(t * B_ + b) * 64 + lane] : 0.f;
    float best = -3e38f; int bp = 0;
    for (int p = 0; p < KTAG; ++p) {         // ascending p + strict '>': first-index
      float cand = (__shfl(score, p) + tr[p * KTAG + lane]) + e;  // ref op order
      if (cand > best) { best = cand; bp = p; }
    }
    if (lane < KTAG) { score = best; hist[t * KTAG + lane] = (unsigned char)bp; }
  }
  if (lane < KTAG) fin[lane] = score + endv[lane];
  __syncthreads();
  if (lane == 0) {
    float bb = -3e38f; int tag = 0;
    for (int p = 0; p < KTAG; ++p)
      if (fin[p] > bb) { bb = fin[p]; tag = p; }
    for (int t = len - 1; t >= 1; --t) {
      outp[t * B_ + b] = tag;
      tag = hist[t * KTAG + tag];
    }
    outp[b] = tag;
  }
  for (int t = len + lane; t < T_; t += 64) outp[t * B_ + b] = 0;
}

// ---------------- diagnostics (slim) ----------------
__global__ void sentinel_fill(int* __restrict__ outp, int val) {
  int i = blockIdx.x * 256 + threadIdx.x;
  if (i < TB_) outp[i] = val;
}
__global__ void diag_init(int* __restrict__ f) { if (threadIdx.x == 0) f[0] = 0; }
__global__ void check_nan(const float* __restrict__ p, long n, int* __restrict__ f) {
  long i0 = (long)blockIdx.x * 256 + threadIdx.x;
  int bad = 0;
  for (long i = i0; i < n; i += (long)gridDim.x * 256)
    if (!(fabsf(p[i]) <= 1e8f)) bad = 1;
  if (bad) atomicOr(&f[0], 1);
}
__global__ void verdict(const int* __restrict__ f, int* __restrict__ outp) {
  if (f[0]) outp[threadIdx.x] = -4096;
}

// ---------------- host ----------------

extern "C" void kernel_launch(void* const* d_in, const int* in_sizes, int n_in,
                              void* d_out, int out_size, void* d_ws, size_t ws_size,
                              hipStream_t stream) {
  int* outp = (int*)d_out;

  static const int exp_sizes[14] = {16384, 64, 15000000, 614400, 524288, 2048,
                                    1048576, 524288, 2048, 10240, 20, 400, 20, 20};
  int badi = (n_in == 14) ? -1 : 14;
  if (badi < 0)
    for (int i = 0; i < 14; ++i)
      if (in_sizes[i] != exp_sizes[i]) { badi = i; break; }
  if (badi >= 0) {
    hipLaunchKernelGGL(sentinel_fill, dim3((TB_ + 255) / 256), dim3(256), 0, stream,
                       outp, -(20000 + badi));
    return;
  }

  const int*   x      = (const int*)d_in[0];
  const int*   lens   = (const int*)d_in[1];
  const float* emb    = (const float*)d_in[2];
  const float* Wih0   = (const float*)d_in[3];
  const float* Whh0   = (const float*)d_in[4];
  const float* b0     = (const float*)d_in[5];
  const float* Wih1   = (const float*)d_in[6];
  const float* Whh1   = (const float*)d_in[7];
  const float* b1     = (const float*)d_in[8];
  const float* Wout   = (const float*)d_in[9];
  const float* bout   = (const float*)d_in[10];
  const float* trans  = (const float*)d_in[11];
  const float* startv = (const float*)d_in[12];
  const float* endv   = (const float*)d_in[13];

  // cascade: hi4 -> hi2 -> lo, gated on proof of residency (no scratch).
  static int chosen = -1;
  if (chosen < 0) {
    chosen = 0;
    hipFuncAttributes fa;
    if (hipFuncGetAttributes(&fa, reinterpret_cast<const void*>(&lstm_rec_hi2)) ==
            hipSuccess &&
        fa.localSizeBytes == 0 && fa.numRegs >= 150)
      chosen = 1;
    if (hipFuncGetAttributes(&fa, reinterpret_cast<const void*>(&lstm_rec_hi4)) ==
            hipSuccess &&
        fa.localSizeBytes == 0 && fa.numRegs >= 150)
      chosen = 2;
  }

  const size_t sz_whh = (size_t)524288 * 4;   // 2 MiB per layer per layout

  const size_t need =
      (size_t)TB_ * 2048 * 4      // xg
    + (size_t)TB_ * EPAD * 4     // xsA
    + (size_t)TB_ * 512 * 4      // outh
    + (size_t)2048 * EPAD * 4    // B0t
    + (size_t)64 * 512 * 4       // Bot
    + 4 * sz_whh                 // whh{0,1} x {U,L}
    + 64 * 4                     // biaso
    + (size_t)TB_ * 64 * 4       // emis
    + 64;                        // diag

  if (ws_size < need) {
    hipLaunchKernelGGL(sentinel_fill, dim3((TB_ + 255) / 256), dim3(256), 0, stream,
                       outp, -(int)(10000 + (ws_size >> 20)));
    return;
  }

  char* w = (char*)d_ws;
  float* xg    = (float*)w;  w += (size_t)TB_ * 2048 * 4;
  float* xsA   = (float*)w;  w += (size_t)TB_ * EPAD * 4;
  float* outh  = (float*)w;  w += (size_t)TB_ * 512 * 4;
  float* B0t   = (float*)w;  w += (size_t)2048 * EPAD * 4;
  float* Bot   = (float*)w;  w += (size_t)64 * 512 * 4;
  float* whh0U = (float*)w;  w += sz_whh;
  float* whh1U = (float*)w;  w += sz_whh;
  float* whh0L = (float*)w;  w += sz_whh;
  float* whh1L = (float*)w;  w += sz_whh;
  float* biaso = (float*)w;  w += 64 * 4;
  float* emis  = (float*)w;  w += (size_t)TB_ * 64 * 4;
  int*   diag  = (int*)w;    w += 64;

  hipLaunchKernelGGL(diag_init, dim3(1), dim3(64), 0, stream, diag);
  hipLaunchKernelGGL(prep_embed, dim3(TB_), dim3(64), 0, stream, x, emb, xsA);
  hipLaunchKernelGGL(prep_b0t, dim3((2048 * EPAD + 255) / 256), dim3(256), 0, stream, Wih0, B0t);
  hipLaunchKernelGGL(prep_bot64, dim3(128), dim3(256), 0, stream, Wout, Bot, bout, biaso);
  if (chosen >= 1) {
    hipLaunchKernelGGL(prep_whh4, dim3(2048), dim3(256), 0, stream, Whh0, whh0U);
    hipLaunchKernelGGL(prep_whh4, dim3(2048), dim3(256), 0, stream, Whh1, whh1U);
  } else {
    hipLaunchKernelGGL(prep_whh2, dim3(2048), dim3(256), 0, stream, Whh0, whh0L);
    hipLaunchKernelGGL(prep_whh2, dim3(2048), dim3(256), 0, stream, Whh1, whh1L);
  }

  // layer 0
  hipLaunchKernelGGL(gemm_f32, dim3(256 * 32), dim3(256), 0, stream,
                     xsA, EPAD, B0t, EPAD, xg, 2048, b0, 32, EPAD);
  if (chosen == 2)
    hipLaunchKernelGGL(lstm_rec_hi4, dim3(128), dim3(512), 0, stream, xg, whh0U, outh, lens);
  else if (chosen == 1)
    hipLaunchKernelGGL(lstm_rec_hi2, dim3(128), dim3(512), 0, stream, xg, whh0U, outh, lens);
  else
    hipLaunchKernelGGL(lstm_rec_lo, dim3(128), dim3(1024), 0, stream, xg, whh0L, outh, lens);
  // layer 1 (Wih1/b1 used directly: [2048][512] row-major, K=512)
  hipLaunchKernelGGL(gemm_f32, dim3(256 * 32), dim3(256), 0, stream,
                     outh, 512, Wih1, 512, xg, 2048, b1, 32, 512);
  if (chosen == 2)
    hipLaunchKernelGGL(lstm_rec_hi4, dim3(128), dim3(512), 0, stream, xg, whh1U, outh, lens);
  else if (chosen == 1)
    hipLaunchKernelGGL(lstm_rec_hi2, dim3(128), dim3(512), 0, stream, xg, whh1U, outh, lens);
  else
    hipLaunchKernelGGL(lstm_rec_lo, dim3(128), dim3(1024), 0, stream, xg, whh1L, outh, lens);
  // emissions (N padded to 64) + decode
  hipLaunchKernelGGL(gemm_f32, dim3(256), dim3(256), 0, stream,
                     outh, 512, Bot, 512, emis, 64, biaso, 1, 512);
  hipLaunchKernelGGL(check_nan, dim3(256), dim3(256), 0, stream,
                     emis, (long)TB_ * 64, diag);
  hipLaunchKernelGGL(viterbi, dim3(B_), dim3(64), 0, stream,
                     emis, trans, startv, endv, lens, outp);
  hipLaunchKernelGGL(verdict, dim3(1), dim3(64), 0, stream, diag, outp);
}

// Round 12
// 3978.621 us; speedup vs baseline: 1.0049x; 1.0049x over previous
//
#include <hip/hip_runtime.h>
#include <stdint.h>

// BiLSTM-CRF on gfx950 — fp32 (validated absmax 0.0). R18: two probe-gated
// changes. (1) lstm hi4b = hi2 with QR2 22->20 (frees 16 regs to fund)
// unroll-4 streamed loop (~8 loads in flight vs 4; hi4/hi3b showed 176 pins
// leave ZERO reg headroom, so buy it by unpinning 2 quads) + QL=9.
// Per-gate q-ascending FP chain unchanged -> bitwise-same h.
// (2) gemm128: 128x128 tile, 8x8/thread (64 FMA : 4 LDS reads vs 16:2) for
// the two big GEMMs; per-output K-chain stays k-ascending -> bitwise-same C.
// Cascades: hi4b -> hi2 -> lo ; gemm128 -> gemm_f32. All fallbacks proven.

#define T_ 256
#define B_ 64
#define EPAD 304
#define KTAG 20
#define TB_ (T_ * B_)

// hi partitions (global k-quads 0..63, q ascending)
#define QR2 22                  // hi2: quads resident per gate-row (176 pinned)
#define QL2A 8                  // hi2: quads in LDS (128 KiB)
#define QS2A 34                 // hi2: streamed
#define QR4B 20                 // hi4b: quads resident (160 pinned)
#define QL4B 9                  // hi4b: quads in LDS (144 KiB)
#define QS4B 35                 // hi4b: streamed

// lo (R8) partition
#define KR_LO 64
#define KLQ_LO 3
#define NQS_LO 45
#define WLDS_OFF_LO (2 * KR_LO * 1024)                    // 131072 floats
#define WSTR_OFF_LO (WLDS_OFF_LO + 2 * KLQ_LO * 1024 * 4) // 155648 floats

__device__ __forceinline__ float rlane(float v, int l) {
  return __int_as_float(__builtin_amdgcn_readlane(__float_as_int(v), l));
}

// ---------------- prep ----------------

__global__ void prep_embed(const int* __restrict__ x, const float* __restrict__ emb,
                           float* __restrict__ xsA) {
  int r = blockIdx.x;
  int tok = x[r];
  const float* src = emb + (size_t)tok * 300;
  for (int e = threadIdx.x; e < EPAD; e += 64)
    xsA[(size_t)r * EPAD + e] = (e < 300) ? src[e] : 0.f;
}

__global__ void prep_b0t(const float* __restrict__ Wih0, float* __restrict__ B0t) {
  int idx = blockIdx.x * 256 + threadIdx.x;
  if (idx >= 2048 * EPAD) return;
  int n = idx / EPAD, k = idx % EPAD;
  B0t[idx] = (k < 300) ? Wih0[(size_t)n * 300 + k] : 0.f;
}

__global__ void prep_bot64(const float* __restrict__ Wout, float* __restrict__ Bot,
                           const float* __restrict__ bout, float* __restrict__ biaso) {
  int idx = blockIdx.x * 256 + threadIdx.x;   // 64*512
  int n = idx >> 9, k = idx & 511;
  Bot[idx] = (n < KTAG) ? Wout[(size_t)n * 512 + k] : 0.f;
  if (idx < 64) biaso[idx] = (idx < KTAG) ? bout[idx] : 0.f;
}

// hi layout: whhU[d][q=k/4][gate][j][e]  (quad-major; lane j reads 16B at j*16)
__global__ void prep_whh4(const float* __restrict__ Whh, float* __restrict__ whhU) {
  int idx = blockIdx.x * 256 + threadIdx.x;   // 524288
  int d = idx >> 18, rem = idx & 262143, row = rem >> 8, k = rem & 255;
  float v = Whh[(size_t)d * 262144 + (size_t)row * 256 + k];
  int gt = row >> 8, j = row & 255;
  int q = k >> 2, e = k & 3;
  whhU[((((size_t)d * 64 + q) * 4 + gt) * 256 + j) * 4 + e] = v;
}

// lo layout (R8): thread tg owns row (tg&3)*256 + (tg>>2)
__global__ void prep_whh2(const float* __restrict__ Whh, float* __restrict__ whhL) {
  int idx = blockIdx.x * 256 + threadIdx.x;   // 524288
  int d = idx >> 18, rem = idx & 262143, k = rem >> 10, tg = rem & 1023;
  int row = (tg & 3) * 256 + (tg >> 2);
  float v = Whh[(size_t)d * 262144 + (size_t)row * 256 + k];
  if (k < KR_LO) {
    whhL[(size_t)(d * KR_LO + k) * 1024 + tg] = v;
  } else if (k < KR_LO + 12) {
    int kk = k - KR_LO, q = kk >> 2, e = kk & 3;
    whhL[WLDS_OFF_LO + (size_t)((d * KLQ_LO + q) * 1024 + tg) * 4 + e] = v;
  } else {
    int kk = k - KR_LO - 12, q = kk >> 2, e = kk & 3;
    whhL[WSTR_OFF_LO + (size_t)((d * NQS_LO + q) * 1024 + tg) * 4 + e] = v;
  }
}

// ---------------- fp32 GEMM (64x64 tile, proven): C = A * Bt^T + bias -------
__global__ __launch_bounds__(256) void gemm_f32(
    const float* __restrict__ A, int lda, const float* __restrict__ Bt, int ldb,
    float* __restrict__ C, int ldc, const float* __restrict__ bias,
    int ntn, int K) {
  const int tm = blockIdx.x / ntn, tn = blockIdx.x % ntn;
  const int m0 = tm * 64, n0 = tn * 64;
  __shared__ __align__(16) float As[16][64];
  __shared__ __align__(16) float Bs[16][64];
  const int tid = threadIdx.x;
  const int mm = tid >> 2, kq = (tid & 3) * 4;
  const int tx = tid & 15, ty = tid >> 4;
  float acc[4][4] = {};
  for (int k0 = 0; k0 < K; k0 += 16) {
    float4 av = *(const float4*)&A[(size_t)(m0 + mm) * lda + k0 + kq];
    float4 bv = *(const float4*)&Bt[(size_t)(n0 + mm) * ldb + k0 + kq];
    __syncthreads();                       // guard prev-iter LDS reads
    As[kq + 0][mm] = av.x; As[kq + 1][mm] = av.y;
    As[kq + 2][mm] = av.z; As[kq + 3][mm] = av.w;
    Bs[kq + 0][mm] = bv.x; Bs[kq + 1][mm] = bv.y;
    Bs[kq + 2][mm] = bv.z; Bs[kq + 3][mm] = bv.w;
    __syncthreads();
#pragma unroll
    for (int kk = 0; kk < 16; ++kk) {
      float4 a4 = *(const float4*)&As[kk][ty * 4];
      float4 b4 = *(const float4*)&Bs[kk][tx * 4];
      acc[0][0] += a4.x * b4.x; acc[0][1] += a4.x * b4.y;
      acc[0][2] += a4.x * b4.z; acc[0][3] += a4.x * b4.w;
      acc[1][0] += a4.y * b4.x; acc[1][1] += a4.y * b4.y;
      acc[1][2] += a4.y * b4.z; acc[1][3] += a4.y * b4.w;
      acc[2][0] += a4.z * b4.x; acc[2][1] += a4.z * b4.y;
      acc[2][2] += a4.z * b4.z; acc[2][3] += a4.z * b4.w;
      acc[3][0] += a4.w * b4.x; acc[3][1] += a4.w * b4.y;
      acc[3][2] += a4.w * b4.z; acc[3][3] += a4.w * b4.w;
    }
  }
#pragma unroll
  for (int i = 0; i < 4; ++i)
#pragma unroll
    for (int j = 0; j < 4; ++j)
      C[(size_t)(m0 + ty * 4 + i) * ldc + n0 + tx * 4 + j] =
          acc[i][j] + bias[n0 + tx * 4 + j];
}

// ---------------- gemm128: 128x128 tile, BK=8, 256 thr, 8x8/thread ----------
// Per-output k-chain: k0 ascending (step 8) x kk ascending -> k ascending,
// identical FP order to gemm_f32 -> bitwise-same C. Requires K%8==0,
// M%128==0, N%128==0 (true for both big GEMMs).
__global__ __attribute__((amdgpu_flat_work_group_size(256, 256),
                          amdgpu_waves_per_eu(4, 4)))
void gemm128(const float* __restrict__ A, int lda, const float* __restrict__ Bt,
             int ldb, float* __restrict__ C, int ldc,
             const float* __restrict__ bias, int ntn, int K) {
  const int tm = blockIdx.x / ntn, tn = blockIdx.x % ntn;
  const int m0 = tm * 128, n0 = tn * 128;
  __shared__ __align__(16) float As[8][128];
  __shared__ __align__(16) float Bs[8][128];
  const int tid = threadIdx.x;
  const int lrow = tid >> 1, lkq = (tid & 1) * 4;   // loader: row 0..127, k 0/4
  const int tx = tid & 15, ty = tid >> 4;           // compute: 8 cols, 8 rows
  float acc[8][8] = {};
  for (int k0 = 0; k0 < K; k0 += 8) {
    float4 av = *(const float4*)&A[(size_t)(m0 + lrow) * lda + k0 + lkq];
    float4 bv = *(const float4*)&Bt[(size_t)(n0 + lrow) * ldb + k0 + lkq];
    __syncthreads();                       // guard prev-iter LDS reads
    As[lkq + 0][lrow] = av.x; As[lkq + 1][lrow] = av.y;
    As[lkq + 2][lrow] = av.z; As[lkq + 3][lrow] = av.w;
    Bs[lkq + 0][lrow] = bv.x; Bs[lkq + 1][lrow] = bv.y;
    Bs[lkq + 2][lrow] = bv.z; Bs[lkq + 3][lrow] = bv.w;
    __syncthreads();
#pragma unroll
    for (int kk = 0; kk < 8; ++kk) {
      float4 a0 = *(const float4*)&As[kk][ty * 8];
      float4 a1 = *(const float4*)&As[kk][ty * 8 + 4];
      float4 b0 = *(const float4*)&Bs[kk][tx * 8];
      float4 b1 = *(const float4*)&Bs[kk][tx * 8 + 4];
      float a[8] = {a0.x, a0.y, a0.z, a0.w, a1.x, a1.y, a1.z, a1.w};
      float bb[8] = {b0.x, b0.y, b0.z, b0.w, b1.x, b1.y, b1.z, b1.w};
#pragma unroll
      for (int i = 0; i < 8; ++i)
#pragma unroll
        for (int j = 0; j < 8; ++j)
          acc[i][j] += a[i] * bb[j];
    }
  }
#pragma unroll
  for (int i = 0; i < 8; ++i)
#pragma unroll
    for (int j = 0; j < 8; ++j)
      C[(size_t)(m0 + ty * 8 + i) * ldc + n0 + tx * 8 + j] =
          acc[i][j] + bias[n0 + tx * 8 + j];
}

// ---------------- hi4b LSTM: hi2 + QR=20 / QL=9 / unroll-4 stream ----------
__global__ __attribute__((amdgpu_flat_work_group_size(512, 512),
                          amdgpu_waves_per_eu(2, 2)))
void lstm_rec_hi4b(const float* __restrict__ xg, const float* __restrict__ whhU,
                   float* __restrict__ out, const int* __restrict__ lens) {
  const int wg = blockIdx.x, d = wg & 1, b = wg >> 1;
  const int len = lens[b];
  const int tg = threadIdx.x;
  const int j = tg & 255, gp = tg >> 8;    // gp 0: gates i,f ; gp 1: gates g,o
  const int g0 = gp * 2;
  const int l = tg & 63;
  const float* wb = whhU + (size_t)d * 64 * 4096;

  float4 wA[QR4B], wB[QR4B];
#pragma unroll
  for (int q = 0; q < QR4B; ++q) {
    wA[q] = *(const float4*)(wb + ((size_t)(q * 4 + g0) * 256 + j) * 4);
    wB[q] = *(const float4*)(wb + ((size_t)(q * 4 + g0 + 1) * 256 + j) * 4);
  }
#pragma unroll
  for (int q = 0; q < QR4B; ++q) {
    asm volatile("" : "+v"(wA[q].x), "+v"(wA[q].y), "+v"(wA[q].z), "+v"(wA[q].w));
    asm volatile("" : "+v"(wB[q].x), "+v"(wB[q].y), "+v"(wB[q].z), "+v"(wB[q].w));
  }

  __shared__ __align__(16) float4 wlds[QL4B][4][256];  // 144 KiB
  __shared__ __align__(16) float hsd[2][256];
  __shared__ __align__(8) float2 exch[256];
  for (int i = tg; i < QL4B * 4 * 256; i += 512) {
    int q3 = i >> 10, g = (i >> 8) & 3, jj = i & 255;
    wlds[q3][g][jj] =
        *(const float4*)(wb + ((size_t)((QR4B + q3) * 4 + g) * 256 + jj) * 4);
  }
  if (tg < 256) hsd[0][tg] = 0.f;
  float c = 0.f;
  __syncthreads();

  for (int s = 0; s < len; ++s) {
    const int t = d ? (len - 1 - s) : s;
    const int rp = t * B_ + b;
    const size_t xb = (size_t)rp * 2048 + d * 1024 + (size_t)g0 * 256 + j;
    float xv0 = xg[xb];
    float xv1 = xg[xb + 256];
    float4 hv = *(const float4*)&hsd[s & 1][l * 4];

    float aA0 = 0.f, aA1 = 0.f, aB0 = 0.f, aB1 = 0.f;
#pragma unroll
    for (int q = 0; q < QR4B; ++q) {       // k ascending = validated FP chain
      float b0 = rlane(hv.x, q), b1 = rlane(hv.y, q);
      float b2 = rlane(hv.z, q), b3 = rlane(hv.w, q);
      aA0 += wA[q].x * b0 + wA[q].y * b1;  aA1 += wA[q].z * b2 + wA[q].w * b3;
      aB0 += wB[q].x * b0 + wB[q].y * b1;  aB1 += wB[q].z * b2 + wB[q].w * b3;
    }
#pragma unroll
    for (int q3 = 0; q3 < QL4B; ++q3) {
      int q = QR4B + q3;
      float b0 = rlane(hv.x, q), b1 = rlane(hv.y, q);
      float b2 = rlane(hv.z, q), b3 = rlane(hv.w, q);
      float4 wa = wlds[q3][g0][j], wbq = wlds[q3][g0 + 1][j];
      aA0 += wa.x * b0 + wa.y * b1;   aA1 += wa.z * b2 + wa.w * b3;
      aB0 += wbq.x * b0 + wbq.y * b1; aB1 += wbq.z * b2 + wbq.w * b3;
    }
#pragma unroll 4
    for (int qs = 0; qs < QS4B; ++qs) {    // deeper unroll: ~8 loads in flight
      int q = QR4B + QL4B + qs;
      float4 wa = *(const float4*)(wb + ((size_t)(q * 4 + g0) * 256 + j) * 4);
      float4 wbq = *(const float4*)(wb + ((size_t)(q * 4 + g0 + 1) * 256 + j) * 4);
      float b0 = rlane(hv.x, q), b1 = rlane(hv.y, q);
      float b2 = rlane(hv.z, q), b3 = rlane(hv.w, q);
      aA0 += wa.x * b0 + wa.y * b1;   aA1 += wa.z * b2 + wa.w * b3;
      aB0 += wbq.x * b0 + wbq.y * b1; aB1 += wbq.z * b2 + wbq.w * b3;
    }

    float aA = aA0 + aA1 + xv0;            // gp0: i ; gp1: g
    float aB = aB0 + aB1 + xv1;            // gp0: f ; gp1: o
    if (gp == 1) exch[j] = make_float2(aA, aB);
    __syncthreads();
    if (gp == 0) {
      float2 go = exch[j];
      float si = 1.f / (1.f + expf(-aA));  // i
      float sf = 1.f / (1.f + expf(-aB));  // f
      float so = 1.f / (1.f + expf(-go.y));// o
      c = sf * c + si * tanhf(go.x);       // g
      float h = so * tanhf(c);
      hsd[(s + 1) & 1][j] = h;
      out[(size_t)rp * 512 + d * 256 + j] = h;
    }
    __syncthreads();
  }
  if (gp == 0)                              // pack_padded: padded outputs zero
    for (int t = len; t < T_; ++t)
      out[(size_t)(t * B_ + b) * 512 + d * 256 + j] = 0.f;
}

// ---------------- hi2 LSTM: R13 verbatim (proven 1551-1571 us) ----------
__global__ __attribute__((amdgpu_flat_work_group_size(512, 512),
                          amdgpu_waves_per_eu(2, 2)))
void lstm_rec_hi2(const float* __restrict__ xg, const float* __restrict__ whhU,
                  float* __restrict__ out, const int* __restrict__ lens) {
  const int wg = blockIdx.x, d = wg & 1, b = wg >> 1;
  const int len = lens[b];
  const int tg = threadIdx.x;
  const int j = tg & 255, gp = tg >> 8;
  const int g0 = gp * 2;
  const int l = tg & 63;
  const float* wb = whhU + (size_t)d * 64 * 4096;

  float4 wA[QR2], wB[QR2];
#pragma unroll
  for (int q = 0; q < QR2; ++q) {
    wA[q] = *(const float4*)(wb + ((size_t)(q * 4 + g0) * 256 + j) * 4);
    wB[q] = *(const float4*)(wb + ((size_t)(q * 4 + g0 + 1) * 256 + j) * 4);
  }
#pragma unroll
  for (int q = 0; q < QR2; ++q) {
    asm volatile("" : "+v"(wA[q].x), "+v"(wA[q].y), "+v"(wA[q].z), "+v"(wA[q].w));
    asm volatile("" : "+v"(wB[q].x), "+v"(wB[q].y), "+v"(wB[q].z), "+v"(wB[q].w));
  }

  __shared__ __align__(16) float4 wlds[QL2A][4][256];  // 128 KiB
  __shared__ __align__(16) float hsd[2][256];
  __shared__ __align__(8) float2 exch[256];
  for (int i = tg; i < QL2A * 4 * 256; i += 512) {
    int q3 = i >> 10, g = (i >> 8) & 3, jj = i & 255;
    wlds[q3][g][jj] =
        *(const float4*)(wb + ((size_t)((QR2 + q3) * 4 + g) * 256 + jj) * 4);
  }
  if (tg < 256) hsd[0][tg] = 0.f;
  float c = 0.f;
  __syncthreads();

  for (int s = 0; s < len; ++s) {
    const int t = d ? (len - 1 - s) : s;
    const int rp = t * B_ + b;
    const size_t xb = (size_t)rp * 2048 + d * 1024 + (size_t)g0 * 256 + j;
    float xv0 = xg[xb];
    float xv1 = xg[xb + 256];
    float4 hv = *(const float4*)&hsd[s & 1][l * 4];

    float aA0 = 0.f, aA1 = 0.f, aB0 = 0.f, aB1 = 0.f;
#pragma unroll
    for (int q = 0; q < QR2; ++q) {
      float b0 = rlane(hv.x, q), b1 = rlane(hv.y, q);
      float b2 = rlane(hv.z, q), b3 = rlane(hv.w, q);
      aA0 += wA[q].x * b0 + wA[q].y * b1;  aA1 += wA[q].z * b2 + wA[q].w * b3;
      aB0 += wB[q].x * b0 + wB[q].y * b1;  aB1 += wB[q].z * b2 + wB[q].w * b3;
    }
#pragma unroll
    for (int q3 = 0; q3 < QL2A; ++q3) {
      int q = QR2 + q3;
      float b0 = rlane(hv.x, q), b1 = rlane(hv.y, q);
      float b2 = rlane(hv.z, q), b3 = rlane(hv.w, q);
      float4 wa = wlds[q3][g0][j], wbq = wlds[q3][g0 + 1][j];
      aA0 += wa.x * b0 + wa.y * b1;   aA1 += wa.z * b2 + wa.w * b3;
      aB0 += wbq.x * b0 + wbq.y * b1; aB1 += wbq.z * b2 + wbq.w * b3;
    }
#pragma unroll 2
    for (int qs = 0; qs < QS2A; ++qs) {
      int q = QR2 + QL2A + qs;
      float4 wa = *(const float4*)(wb + ((size_t)(q * 4 + g0) * 256 + j) * 4);
      float4 wbq = *(const float4*)(wb + ((size_t)(q * 4 + g0 + 1) * 256 + j) * 4);
      float b0 = rlane(hv.x, q), b1 = rlane(hv.y, q);
      float b2 = rlane(hv.z, q), b3 = rlane(hv.w, q);
      aA0 += wa.x * b0 + wa.y * b1;   aA1 += wa.z * b2 + wa.w * b3;
      aB0 += wbq.x * b0 + wbq.y * b1; aB1 += wbq.z * b2 + wbq.w * b3;
    }

    float aA = aA0 + aA1 + xv0;
    float aB = aB0 + aB1 + xv1;
    if (gp == 1) exch[j] = make_float2(aA, aB);
    __syncthreads();
    if (gp == 0) {
      float2 go = exch[j];
      float si = 1.f / (1.f + expf(-aA));
      float sf = 1.f / (1.f + expf(-aB));
      float so = 1.f / (1.f + expf(-go.y));
      c = sf * c + si * tanhf(go.x);
      float h = so * tanhf(c);
      hsd[(s + 1) & 1][j] = h;
      out[(size_t)rp * 512 + d * 256 + j] = h;
    }
    __syncthreads();
  }
  if (gp == 0)
    for (int t = len; t < T_; ++t)
      out[(size_t)(t * B_ + b) * 512 + d * 256 + j] = 0.f;
}

// ---------------- lo LSTM: verbatim R8 (proven 1963 us, absmax 0.0) ----------
__global__ __launch_bounds__(1024, 4) void lstm_rec_lo(
    const float* __restrict__ xg, const float* __restrict__ whhL,
    float* __restrict__ out, const int* __restrict__ lens) {
  const int wg = blockIdx.x, dir = wg & 1, b = wg >> 1;
  const int len = lens[b];
  const int tg = threadIdx.x;
  const int j = tg >> 2, gt = tg & 3;
  const int row = gt * 256 + j;

  float wres[KR_LO];
#pragma unroll
  for (int k = 0; k < KR_LO; ++k)
    wres[k] = whhL[(size_t)(dir * KR_LO + k) * 1024 + tg];

  __shared__ __align__(16) float4 wlds[KLQ_LO][1024];
  __shared__ __align__(16) float hsd[2][256];
#pragma unroll
  for (int q = 0; q < KLQ_LO; ++q)
    wlds[q][tg] = *(const float4*)&whhL[WLDS_OFF_LO + (size_t)((dir * KLQ_LO + q) * 1024 + tg) * 4];
  if (tg < 256) hsd[0][tg] = 0.f;
  float c = 0.f;
  __syncthreads();

  const float* sp = whhL + WSTR_OFF_LO + (size_t)dir * NQS_LO * 4096 + (size_t)tg * 4;
  const int lane = tg & 63, qb = lane & ~3;

  for (int s = 0; s < len; ++s) {
    const int t = dir ? (len - 1 - s) : s;
    const int rp = t * B_ + b;
    float xv = xg[(size_t)rp * 2048 + dir * 1024 + row];
    float4 hv = *(const float4*)&hsd[s & 1][lane * 4];

    float acc0 = 0.f, acc1 = 0.f;
#pragma unroll
    for (int q = 0; q < KR_LO / 4; ++q) {
      float b0 = rlane(hv.x, q), b1 = rlane(hv.y, q);
      float b2 = rlane(hv.z, q), b3 = rlane(hv.w, q);
      acc0 += wres[4 * q + 0] * b0 + wres[4 * q + 1] * b1;
      acc1 += wres[4 * q + 2] * b2 + wres[4 * q + 3] * b3;
    }
#pragma unroll
    for (int q3 = 0; q3 < KLQ_LO; ++q3) {
      int q = KR_LO / 4 + q3;
      float4 wl = wlds[q3][tg];
      float b0 = rlane(hv.x, q), b1 = rlane(hv.y, q);
      float b2 = rlane(hv.z, q), b3 = rlane(hv.w, q);
      acc0 += wl.x * b0 + wl.y * b1;
      acc1 += wl.z * b2 + wl.w * b3;
    }
#pragma unroll 5
    for (int qq = 0; qq < NQS_LO; ++qq) {
      int q = KR_LO / 4 + KLQ_LO + qq;
      float4 wv = *(const float4*)(sp + (size_t)qq * 4096);
      float b0 = rlane(hv.x, q), b1 = rlane(hv.y, q);
      float b2 = rlane(hv.z, q), b3 = rlane(hv.w, q);
      acc0 += wv.x * b0 + wv.y * b1;
      acc1 += wv.z * b2 + wv.w * b3;
    }

    float a = acc0 + acc1 + xv;
    float v1 = __shfl(a, qb | 1);
    float v2 = __shfl(a, qb | 2);
    float v3 = __shfl(a, qb | 3);
    if (gt == 0) {
      float si = 1.f / (1.f + expf(-a));
      float sf = 1.f / (1.f + expf(-v1));
      float so = 1.f / (1.f + expf(-v3));
      c = sf * c + si * tanhf(v2);
      float h = so * tanhf(c);
      hsd[(s + 1) & 1][j] = h;
      out[(size_t)rp * 512 + dir * 256 + j] = h;
    }
    __syncthreads();
  }
  for (int t = len; t < T_; ++t)
    if (gt == 0) out[(size_t)(t * B_ + b) * 512 + dir * 256 + j] = 0.f;
}

// ---------------- Viterbi (one wave per batch; ref fp-op order) ----------------
__global__ __launch_bounds__(64) void viterbi(
    const float* __restrict__ emis, const float* __restrict__ trans,
    const float* __restrict__ startv, const float* __restrict__ endv,
    const int* __restrict__ lens, int* __restrict__ outp) {
  int b = blockIdx.x, lane = threadIdx.x;
  __shared__ float tr[KTAG * KTAG];
  __shared__ float fin[KTAG];
  __shared__ unsigned char hist[T_ * KTAG];
  for (int i = lane; i < KTAG * KTAG; i += 64) tr[i] = trans[i];
  int len = lens[b];
  float score = (lane < KTAG) ? startv[lane] + emis[(size_t)b * 64 + lane] : -3e38f;
  __syncthreads();
  for (int t = 1; t < len; ++t) {
    float e = (lane < KTAG) ? emis[(size_t)(t * B_ + b) * 64 + lane] : 0.f;
    float best = -3e38f; int bp = 0;
    for (int p = 0; p < KTAG; ++p) {         // ascending p + strict '>': first-index
      float cand = (__shfl(score, p) + tr[p * KTAG + lane]) + e;  // ref op order
      if (cand > best) { best = cand; bp = p; }
    }
    if (lane < KTAG) { score = best; hist[t * KTAG + lane] = (unsigned char)bp; }
  }
  if (lane < KTAG) fin[lane] = score + endv[lane];
  __syncthreads();
  if (lane == 0) {
    float bb = -3e38f; int tag = 0;
    for (int p = 0; p < KTAG; ++p)
      if (fin[p] > bb) { bb = fin[p]; tag = p; }
    for (int t = len - 1; t >= 1; --t) {
      outp[t * B_ + b] = tag;
      tag = hist[t * KTAG + tag];
    }
    outp[b] = tag;
  }
  for (int t = len + lane; t < T_; t += 64) outp[t * B_ + b] = 0;
}

// ---------------- diagnostics (slim) ----------------
__global__ void sentinel_fill(int* __restrict__ outp, int val) {
  int i = blockIdx.x * 256 + threadIdx.x;
  if (i < TB_) outp[i] = val;
}
__global__ void diag_init(int* __restrict__ f) { if (threadIdx.x == 0) f[0] = 0; }
__global__ void check_nan(const float* __restrict__ p, long n, int* __restrict__ f) {
  long i0 = (long)blockIdx.x * 256 + threadIdx.x;
  int bad = 0;
  for (long i = i0; i < n; i += (long)gridDim.x * 256)
    if (!(fabsf(p[i]) <= 1e8f)) bad = 1;
  if (bad) atomicOr(&f[0], 1);
}
__global__ void verdict(const int* __restrict__ f, int* __restrict__ outp) {
  if (f[0]) outp[threadIdx.x] = -4096;
}

// ---------------- host ----------------

extern "C" void kernel_launch(void* const* d_in, const int* in_sizes, int n_in,
                              void* d_out, int out_size, void* d_ws, size_t ws_size,
                              hipStream_t stream) {
  int* outp = (int*)d_out;

  static const int exp_sizes[14] = {16384, 64, 15000000, 614400, 524288, 2048,
                                    1048576, 524288, 2048, 10240, 20, 400, 20, 20};
  int badi = (n_in == 14) ? -1 : 14;
  if (badi < 0)
    for (int i = 0; i < 14; ++i)
      if (in_sizes[i] != exp_sizes[i]) { badi = i; break; }
  if (badi >= 0) {
    hipLaunchKernelGGL(sentinel_fill, dim3((TB_ + 255) / 256), dim3(256), 0, stream,
                       outp, -(20000 + badi));
    return;
  }

  const int*   x      = (const int*)d_in[0];
  const int*   lens   = (const int*)d_in[1];
  const float* emb    = (const float*)d_in[2];
  const float* Wih0   = (const float*)d_in[3];
  const float* Whh0   = (const float*)d_in[4];
  const float* b0     = (const float*)d_in[5];
  const float* Wih1   = (const float*)d_in[6];
  const float* Whh1   = (const float*)d_in[7];
  const float* b1     = (const float*)d_in[8];
  const float* Wout   = (const float*)d_in[9];
  const float* bout   = (const float*)d_in[10];
  const float* trans  = (const float*)d_in[11];
  const float* startv = (const float*)d_in[12];
  const float* endv   = (const float*)d_in[13];

  // cascades gated on proof of residency (no scratch).
  static int chosen = -1, guse = -1;
  if (chosen < 0) {
    chosen = 0;
    hipFuncAttributes fa;
    if (hipFuncGetAttributes(&fa, reinterpret_cast<const void*>(&lstm_rec_hi2)) ==
            hipSuccess &&
        fa.localSizeBytes == 0 && fa.numRegs >= 150)
      chosen = 1;
    if (hipFuncGetAttributes(&fa, reinterpret_cast<const void*>(&lstm_rec_hi4b)) ==
            hipSuccess &&
        fa.localSizeBytes == 0 && fa.numRegs >= 140)
      chosen = 2;
    guse = 0;
    if (hipFuncGetAttributes(&fa, reinterpret_cast<const void*>(&gemm128)) ==
            hipSuccess &&
        fa.localSizeBytes == 0 && fa.numRegs >= 80)
      guse = 1;
  }

  const size_t sz_whh = (size_t)524288 * 4;   // 2 MiB per layer per layout

  const size_t need =
      (size_t)TB_ * 2048 * 4      // xg
    + (size_t)TB_ * EPAD * 4     // xsA
    + (size_t)TB_ * 512 * 4      // outh
    + (size_t)2048 * EPAD * 4    // B0t
    + (size_t)64 * 512 * 4       // Bot
    + 4 * sz_whh                 // whh{0,1} x {U,L}
    + 64 * 4                     // biaso
    + (size_t)TB_ * 64 * 4       // emis
    + 64;                        // diag

  if (ws_size < need) {
    hipLaunchKernelGGL(sentinel_fill, dim3((TB_ + 255) / 256), dim3(256), 0, stream,
                       outp, -(int)(10000 + (ws_size >> 20)));
    return;
  }

  char* w = (char*)d_ws;
  float* xg    = (float*)w;  w += (size_t)TB_ * 2048 * 4;
  float* xsA   = (float*)w;  w += (size_t)TB_ * EPAD * 4;
  float* outh  = (float*)w;  w += (size_t)TB_ * 512 * 4;
  float* B0t   = (float*)w;  w += (size_t)2048 * EPAD * 4;
  float* Bot   = (float*)w;  w += (size_t)64 * 512 * 4;
  float* whh0U = (float*)w;  w += sz_whh;
  float* whh1U = (float*)w;  w += sz_whh;
  float* whh0L = (float*)w;  w += sz_whh;
  float* whh1L = (float*)w;  w += sz_whh;
  float* biaso = (float*)w;  w += 64 * 4;
  float* emis  = (float*)w;  w += (size_t)TB_ * 64 * 4;
  int*   diag  = (int*)w;    w += 64;

  hipLaunchKernelGGL(diag_init, dim3(1), dim3(64), 0, stream, diag);
  hipLaunchKernelGGL(prep_embed, dim3(TB_), dim3(64), 0, stream, x, emb, xsA);
  hipLaunchKernelGGL(prep_b0t, dim3((2048 * EPAD + 255) / 256), dim3(256), 0, stream, Wih0, B0t);
  hipLaunchKernelGGL(prep_bot64, dim3(128), dim3(256), 0, stream, Wout, Bot, bout, biaso);
  if (chosen >= 1) {
    hipLaunchKernelGGL(prep_whh4, dim3(2048), dim3(256), 0, stream, Whh0, whh0U);
    hipLaunchKernelGGL(prep_whh4, dim3(2048), dim3(256), 0, stream, Whh1, whh1U);
  } else {
    hipLaunchKernelGGL(prep_whh2, dim3(2048), dim3(256), 0, stream, Whh0, whh0L);
    hipLaunchKernelGGL(prep_whh2, dim3(2048), dim3(256), 0, stream, Whh1, whh1L);
  }

  // layer 0 input GEMM (M=16384, N=2048, K=304)
  if (guse)
    hipLaunchKernelGGL(gemm128, dim3(128 * 16), dim3(256), 0, stream,
                       xsA, EPAD, B0t, EPAD, xg, 2048, b0, 16, EPAD);
  else
    hipLaunchKernelGGL(gemm_f32, dim3(256 * 32), dim3(256), 0, stream,
                       xsA, EPAD, B0t, EPAD, xg, 2048, b0, 32, EPAD);
  if (chosen == 2)
    hipLaunchKernelGGL(lstm_rec_hi4b, dim3(128), dim3(512), 0, stream, xg, whh0U, outh, lens);
  else if (chosen == 1)
    hipLaunchKernelGGL(lstm_rec_hi2, dim3(128), dim3(512), 0, stream, xg, whh0U, outh, lens);
  else
    hipLaunchKernelGGL(lstm_rec_lo, dim3(128), dim3(1024), 0, stream, xg, whh0L, outh, lens);
  // layer 1 input GEMM (M=16384, N=2048, K=512)
  if (guse)
    hipLaunchKernelGGL(gemm128, dim3(128 * 16), dim3(256), 0, stream,
                       outh, 512, Wih1, 512, xg, 2048, b1, 16, 512);
  else
    hipLaunchKernelGGL(gemm_f32, dim3(256 * 32), dim3(256), 0, stream,
                       outh, 512, Wih1, 512, xg, 2048, b1, 32, 512);
  if (chosen == 2)
    hipLaunchKernelGGL(lstm_rec_hi4b, dim3(128), dim3(512), 0, stream, xg, whh1U, outh, lens);
  else if (chosen == 1)
    hipLaunchKernelGGL(lstm_rec_hi2, dim3(128), dim3(512), 0, stream, xg, whh1U, outh, lens);
  else
    hipLaunchKernelGGL(lstm_rec_lo, dim3(128), dim3(1024), 0, stream, xg, whh1L, outh, lens);
  // emissions (N padded to 64) + decode
  hipLaunchKernelGGL(gemm_f32, dim3(256), dim3(256), 0, stream,
                     outh, 512, Bot, 512, emis, 64, biaso, 1, 512);
  hipLaunchKernelGGL(check_nan, dim3(256), dim3(256), 0, stream,
                     emis, (long)TB_ * 64, diag);
  hipLaunchKernelGGL(viterbi, dim3(B_), dim3(64), 0, stream,
                     emis, trans, startv, endv, lens, outp);
  hipLaunchKernelGGL(verdict, dim3(1), dim3(64), 0, stream, diag, outp);
}

// Round 13
// 3930.359 us; speedup vs baseline: 1.0172x; 1.0123x over previous
//
#include <hip/hip_runtime.h>
#include <stdint.h>

// BiLSTM-CRF on gfx950 — fp32 (validated absmax 0.0). R19: (1) gemm_mid
// 128x64-tile 8x4/thread (32 acc regs, plain launch_bounds(256) — NO
// attribute games after gemm128's probe failure) for the two big GEMMs:
// 32 FMA : 3 LDS-b128 vs 16:2 -> ~700 -> ~460 us. k-ascending chain ->
// bitwise-same C. (2) lstm hi4c = hi2 with QR 22->16 (-48 pin regs) funding
// unroll-4 stream (+32 in-flight) = net -16 vs hi2's exactly-at-256 budget
// (R18 lesson: hi4b was +16 over -> scratch). Cascades with proven fallbacks.

#define T_ 256
#define B_ 64
#define EPAD 304
#define KTAG 20
#define TB_ (T_ * B_)

// hi partitions (global k-quads 0..63, q ascending)
#define QR2 22                  // hi2: quads resident per gate-row (176 pinned)
#define QL2A 8                  // hi2: quads in LDS (128 KiB)
#define QS2A 34                 // hi2: streamed
#define QR4C 16                 // hi4c: quads resident (128 pinned)
#define QL4C 9                  // hi4c: quads in LDS (144 KiB)
#define QS4C 39                 // hi4c: streamed

// lo (R8) partition
#define KR_LO 64
#define KLQ_LO 3
#define NQS_LO 45
#define WLDS_OFF_LO (2 * KR_LO * 1024)                    // 131072 floats
#define WSTR_OFF_LO (WLDS_OFF_LO + 2 * KLQ_LO * 1024 * 4) // 155648 floats

__device__ __forceinline__ float rlane(float v, int l) {
  return __int_as_float(__builtin_amdgcn_readlane(__float_as_int(v), l));
}

// ---------------- prep ----------------

__global__ void prep_embed(const int* __restrict__ x, const float* __restrict__ emb,
                           float* __restrict__ xsA) {
  int r = blockIdx.x;
  int tok = x[r];
  const float* src = emb + (size_t)tok * 300;
  for (int e = threadIdx.x; e < EPAD; e += 64)
    xsA[(size_t)r * EPAD + e] = (e < 300) ? src[e] : 0.f;
}

__global__ void prep_b0t(const float* __restrict__ Wih0, float* __restrict__ B0t) {
  int idx = blockIdx.x * 256 + threadIdx.x;
  if (idx >= 2048 * EPAD) return;
  int n = idx / EPAD, k = idx % EPAD;
  B0t[idx] = (k < 300) ? Wih0[(size_t)n * 300 + k] : 0.f;
}

__global__ void prep_bot64(const float* __restrict__ Wout, float* __restrict__ Bot,
                           const float* __restrict__ bout, float* __restrict__ biaso) {
  int idx = blockIdx.x * 256 + threadIdx.x;   // 64*512
  int n = idx >> 9, k = idx & 511;
  Bot[idx] = (n < KTAG) ? Wout[(size_t)n * 512 + k] : 0.f;
  if (idx < 64) biaso[idx] = (idx < KTAG) ? bout[idx] : 0.f;
}

// hi layout: whhU[d][q=k/4][gate][j][e]  (quad-major; lane j reads 16B at j*16)
__global__ void prep_whh4(const float* __restrict__ Whh, float* __restrict__ whhU) {
  int idx = blockIdx.x * 256 + threadIdx.x;   // 524288
  int d = idx >> 18, rem = idx & 262143, row = rem >> 8, k = rem & 255;
  float v = Whh[(size_t)d * 262144 + (size_t)row * 256 + k];
  int gt = row >> 8, j = row & 255;
  int q = k >> 2, e = k & 3;
  whhU[((((size_t)d * 64 + q) * 4 + gt) * 256 + j) * 4 + e] = v;
}

// lo layout (R8): thread tg owns row (tg&3)*256 + (tg>>2)
__global__ void prep_whh2(const float* __restrict__ Whh, float* __restrict__ whhL) {
  int idx = blockIdx.x * 256 + threadIdx.x;   // 524288
  int d = idx >> 18, rem = idx & 262143, k = rem >> 10, tg = rem & 1023;
  int row = (tg & 3) * 256 + (tg >> 2);
  float v = Whh[(size_t)d * 262144 + (size_t)row * 256 + k];
  if (k < KR_LO) {
    whhL[(size_t)(d * KR_LO + k) * 1024 + tg] = v;
  } else if (k < KR_LO + 12) {
    int kk = k - KR_LO, q = kk >> 2, e = kk & 3;
    whhL[WLDS_OFF_LO + (size_t)((d * KLQ_LO + q) * 1024 + tg) * 4 + e] = v;
  } else {
    int kk = k - KR_LO - 12, q = kk >> 2, e = kk & 3;
    whhL[WSTR_OFF_LO + (size_t)((d * NQS_LO + q) * 1024 + tg) * 4 + e] = v;
  }
}

// ---------------- fp32 GEMM (64x64 tile, proven): C = A * Bt^T + bias -------
__global__ __launch_bounds__(256) void gemm_f32(
    const float* __restrict__ A, int lda, const float* __restrict__ Bt, int ldb,
    float* __restrict__ C, int ldc, const float* __restrict__ bias,
    int ntn, int K) {
  const int tm = blockIdx.x / ntn, tn = blockIdx.x % ntn;
  const int m0 = tm * 64, n0 = tn * 64;
  __shared__ __align__(16) float As[16][64];
  __shared__ __align__(16) float Bs[16][64];
  const int tid = threadIdx.x;
  const int mm = tid >> 2, kq = (tid & 3) * 4;
  const int tx = tid & 15, ty = tid >> 4;
  float acc[4][4] = {};
  for (int k0 = 0; k0 < K; k0 += 16) {
    float4 av = *(const float4*)&A[(size_t)(m0 + mm) * lda + k0 + kq];
    float4 bv = *(const float4*)&Bt[(size_t)(n0 + mm) * ldb + k0 + kq];
    __syncthreads();                       // guard prev-iter LDS reads
    As[kq + 0][mm] = av.x; As[kq + 1][mm] = av.y;
    As[kq + 2][mm] = av.z; As[kq + 3][mm] = av.w;
    Bs[kq + 0][mm] = bv.x; Bs[kq + 1][mm] = bv.y;
    Bs[kq + 2][mm] = bv.z; Bs[kq + 3][mm] = bv.w;
    __syncthreads();
#pragma unroll
    for (int kk = 0; kk < 16; ++kk) {
      float4 a4 = *(const float4*)&As[kk][ty * 4];
      float4 b4 = *(const float4*)&Bs[kk][tx * 4];
      acc[0][0] += a4.x * b4.x; acc[0][1] += a4.x * b4.y;
      acc[0][2] += a4.x * b4.z; acc[0][3] += a4.x * b4.w;
      acc[1][0] += a4.y * b4.x; acc[1][1] += a4.y * b4.y;
      acc[1][2] += a4.y * b4.z; acc[1][3] += a4.y * b4.w;
      acc[2][0] += a4.z * b4.x; acc[2][1] += a4.z * b4.y;
      acc[2][2] += a4.z * b4.z; acc[2][3] += a4.z * b4.w;
      acc[3][0] += a4.w * b4.x; acc[3][1] += a4.w * b4.y;
      acc[3][2] += a4.w * b4.z; acc[3][3] += a4.w * b4.w;
    }
  }
#pragma unroll
  for (int i = 0; i < 4; ++i)
#pragma unroll
    for (int j = 0; j < 4; ++j)
      C[(size_t)(m0 + ty * 4 + i) * ldc + n0 + tx * 4 + j] =
          acc[i][j] + bias[n0 + tx * 4 + j];
}

// ---------------- gemm_mid: 128x64 tile, BK=16, 256 thr, 8x4/thread ---------
// 32 FMA : 3 LDS-b128 per kk (vs 16:2). Per-output k-chain ascending ->
// bitwise-same C as gemm_f32. Requires M%128==0, N%64==0, K%16==0.
__global__ __launch_bounds__(256) void gemm_mid(
    const float* __restrict__ A, int lda, const float* __restrict__ Bt, int ldb,
    float* __restrict__ C, int ldc, const float* __restrict__ bias,
    int ntn, int K) {
  const int tm = blockIdx.x / ntn, tn = blockIdx.x % ntn;
  const int m0 = tm * 128, n0 = tn * 64;
  __shared__ __align__(16) float As[16][128];   // 8 KiB
  __shared__ __align__(16) float Bs[16][64];    // 4 KiB
  const int tid = threadIdx.x;
  const int arow = tid >> 1, akq = (tid & 1) * 8;   // A loader: 2 float4
  const int brow = tid >> 2, bkq = (tid & 3) * 4;   // B loader: 1 float4
  const int tx = tid & 15, ty = tid >> 4;           // 4 cols, 8 rows
  float acc[8][4] = {};
  for (int k0 = 0; k0 < K; k0 += 16) {
    float4 av0 = *(const float4*)&A[(size_t)(m0 + arow) * lda + k0 + akq];
    float4 av1 = *(const float4*)&A[(size_t)(m0 + arow) * lda + k0 + akq + 4];
    float4 bv = *(const float4*)&Bt[(size_t)(n0 + brow) * ldb + k0 + bkq];
    __syncthreads();                       // guard prev-iter LDS reads
    As[akq + 0][arow] = av0.x; As[akq + 1][arow] = av0.y;
    As[akq + 2][arow] = av0.z; As[akq + 3][arow] = av0.w;
    As[akq + 4][arow] = av1.x; As[akq + 5][arow] = av1.y;
    As[akq + 6][arow] = av1.z; As[akq + 7][arow] = av1.w;
    Bs[bkq + 0][brow] = bv.x; Bs[bkq + 1][brow] = bv.y;
    Bs[bkq + 2][brow] = bv.z; Bs[bkq + 3][brow] = bv.w;
    __syncthreads();
#pragma unroll
    for (int kk = 0; kk < 16; ++kk) {
      float4 a0 = *(const float4*)&As[kk][ty * 8];
      float4 a1 = *(const float4*)&As[kk][ty * 8 + 4];
      float4 b4 = *(const float4*)&Bs[kk][tx * 4];
      acc[0][0] += a0.x * b4.x; acc[0][1] += a0.x * b4.y;
      acc[0][2] += a0.x * b4.z; acc[0][3] += a0.x * b4.w;
      acc[1][0] += a0.y * b4.x; acc[1][1] += a0.y * b4.y;
      acc[1][2] += a0.y * b4.z; acc[1][3] += a0.y * b4.w;
      acc[2][0] += a0.z * b4.x; acc[2][1] += a0.z * b4.y;
      acc[2][2] += a0.z * b4.z; acc[2][3] += a0.z * b4.w;
      acc[3][0] += a0.w * b4.x; acc[3][1] += a0.w * b4.y;
      acc[3][2] += a0.w * b4.z; acc[3][3] += a0.w * b4.w;
      acc[4][0] += a1.x * b4.x; acc[4][1] += a1.x * b4.y;
      acc[4][2] += a1.x * b4.z; acc[4][3] += a1.x * b4.w;
      acc[5][0] += a1.y * b4.x; acc[5][1] += a1.y * b4.y;
      acc[5][2] += a1.y * b4.z; acc[5][3] += a1.y * b4.w;
      acc[6][0] += a1.z * b4.x; acc[6][1] += a1.z * b4.y;
      acc[6][2] += a1.z * b4.z; acc[6][3] += a1.z * b4.w;
      acc[7][0] += a1.w * b4.x; acc[7][1] += a1.w * b4.y;
      acc[7][2] += a1.w * b4.z; acc[7][3] += a1.w * b4.w;
    }
  }
#pragma unroll
  for (int i = 0; i < 8; ++i)
#pragma unroll
    for (int j = 0; j < 4; ++j)
      C[(size_t)(m0 + ty * 8 + i) * ldc + n0 + tx * 4 + j] =
          acc[i][j] + bias[n0 + tx * 4 + j];
}

// ---------------- hi4c LSTM: hi2 + QR=16 / QL=9 / unroll-4 stream ----------
// Net register demand -16 vs hi2 (which sits exactly at the 256 budget).
__global__ __attribute__((amdgpu_flat_work_group_size(512, 512),
                          amdgpu_waves_per_eu(2, 2)))
void lstm_rec_hi4c(const float* __restrict__ xg, const float* __restrict__ whhU,
                   float* __restrict__ out, const int* __restrict__ lens) {
  const int wg = blockIdx.x, d = wg & 1, b = wg >> 1;
  const int len = lens[b];
  const int tg = threadIdx.x;
  const int j = tg & 255, gp = tg >> 8;    // gp 0: gates i,f ; gp 1: gates g,o
  const int g0 = gp * 2;
  const int l = tg & 63;
  const float* wb = whhU + (size_t)d * 64 * 4096;

  float4 wA[QR4C], wB[QR4C];
#pragma unroll
  for (int q = 0; q < QR4C; ++q) {
    wA[q] = *(const float4*)(wb + ((size_t)(q * 4 + g0) * 256 + j) * 4);
    wB[q] = *(const float4*)(wb + ((size_t)(q * 4 + g0 + 1) * 256 + j) * 4);
  }
#pragma unroll
  for (int q = 0; q < QR4C; ++q) {
    asm volatile("" : "+v"(wA[q].x), "+v"(wA[q].y), "+v"(wA[q].z), "+v"(wA[q].w));
    asm volatile("" : "+v"(wB[q].x), "+v"(wB[q].y), "+v"(wB[q].z), "+v"(wB[q].w));
  }

  __shared__ __align__(16) float4 wlds[QL4C][4][256];  // 144 KiB
  __shared__ __align__(16) float hsd[2][256];
  __shared__ __align__(8) float2 exch[256];
  for (int i = tg; i < QL4C * 4 * 256; i += 512) {
    int q3 = i >> 10, g = (i >> 8) & 3, jj = i & 255;
    wlds[q3][g][jj] =
        *(const float4*)(wb + ((size_t)((QR4C + q3) * 4 + g) * 256 + jj) * 4);
  }
  if (tg < 256) hsd[0][tg] = 0.f;
  float c = 0.f;
  __syncthreads();

  for (int s = 0; s < len; ++s) {
    const int t = d ? (len - 1 - s) : s;
    const int rp = t * B_ + b;
    const size_t xb = (size_t)rp * 2048 + d * 1024 + (size_t)g0 * 256 + j;
    float xv0 = xg[xb];
    float xv1 = xg[xb + 256];
    float4 hv = *(const float4*)&hsd[s & 1][l * 4];

    float aA0 = 0.f, aA1 = 0.f, aB0 = 0.f, aB1 = 0.f;
#pragma unroll
    for (int q = 0; q < QR4C; ++q) {       // k ascending = validated FP chain
      float b0 = rlane(hv.x, q), b1 = rlane(hv.y, q);
      float b2 = rlane(hv.z, q), b3 = rlane(hv.w, q);
      aA0 += wA[q].x * b0 + wA[q].y * b1;  aA1 += wA[q].z * b2 + wA[q].w * b3;
      aB0 += wB[q].x * b0 + wB[q].y * b1;  aB1 += wB[q].z * b2 + wB[q].w * b3;
    }
#pragma unroll
    for (int q3 = 0; q3 < QL4C; ++q3) {
      int q = QR4C + q3;
      float b0 = rlane(hv.x, q), b1 = rlane(hv.y, q);
      float b2 = rlane(hv.z, q), b3 = rlane(hv.w, q);
      float4 wa = wlds[q3][g0][j], wbq = wlds[q3][g0 + 1][j];
      aA0 += wa.x * b0 + wa.y * b1;   aA1 += wa.z * b2 + wa.w * b3;
      aB0 += wbq.x * b0 + wbq.y * b1; aB1 += wbq.z * b2 + wbq.w * b3;
    }
#pragma unroll 4
    for (int qs = 0; qs < QS4C; ++qs) {    // deeper unroll: ~8 loads in flight
      int q = QR4C + QL4C + qs;
      float4 wa = *(const float4*)(wb + ((size_t)(q * 4 + g0) * 256 + j) * 4);
      float4 wbq = *(const float4*)(wb + ((size_t)(q * 4 + g0 + 1) * 256 + j) * 4);
      float b0 = rlane(hv.x, q), b1 = rlane(hv.y, q);
      float b2 = rlane(hv.z, q), b3 = rlane(hv.w, q);
      aA0 += wa.x * b0 + wa.y * b1;   aA1 += wa.z * b2 + wa.w * b3;
      aB0 += wbq.x * b0 + wbq.y * b1; aB1 += wbq.z * b2 + wbq.w * b3;
    }

    float aA = aA0 + aA1 + xv0;            // gp0: i ; gp1: g
    float aB = aB0 + aB1 + xv1;            // gp0: f ; gp1: o
    if (gp == 1) exch[j] = make_float2(aA, aB);
    __syncthreads();
    if (gp == 0) {
      float2 go = exch[j];
      float si = 1.f / (1.f + expf(-aA));  // i
      float sf = 1.f / (1.f + expf(-aB));  // f
      float so = 1.f / (1.f + expf(-go.y));// o
      c = sf * c + si * tanhf(go.x);       // g
      float h = so * tanhf(c);
      hsd[(s + 1) & 1][j] = h;
      out[(size_t)rp * 512 + d * 256 + j] = h;
    }
    __syncthreads();
  }
  if (gp == 0)                              // pack_padded: padded outputs zero
    for (int t = len; t < T_; ++t)
      out[(size_t)(t * B_ + b) * 512 + d * 256 + j] = 0.f;
}

// ---------------- hi2 LSTM: R13 verbatim (proven 1546-1571 us) ----------
__global__ __attribute__((amdgpu_flat_work_group_size(512, 512),
                          amdgpu_waves_per_eu(2, 2)))
void lstm_rec_hi2(const float* __restrict__ xg, const float* __restrict__ whhU,
                  float* __restrict__ out, const int* __restrict__ lens) {
  const int wg = blockIdx.x, d = wg & 1, b = wg >> 1;
  const int len = lens[b];
  const int tg = threadIdx.x;
  const int j = tg & 255, gp = tg >> 8;
  const int g0 = gp * 2;
  const int l = tg & 63;
  const float* wb = whhU + (size_t)d * 64 * 4096;

  float4 wA[QR2], wB[QR2];
#pragma unroll
  for (int q = 0; q < QR2; ++q) {
    wA[q] = *(const float4*)(wb + ((size_t)(q * 4 + g0) * 256 + j) * 4);
    wB[q] = *(const float4*)(wb + ((size_t)(q * 4 + g0 + 1) * 256 + j) * 4);
  }
#pragma unroll
  for (int q = 0; q < QR2; ++q) {
    asm volatile("" : "+v"(wA[q].x), "+v"(wA[q].y), "+v"(wA[q].z), "+v"(wA[q].w));
    asm volatile("" : "+v"(wB[q].x), "+v"(wB[q].y), "+v"(wB[q].z), "+v"(wB[q].w));
  }

  __shared__ __align__(16) float4 wlds[QL2A][4][256];  // 128 KiB
  __shared__ __align__(16) float hsd[2][256];
  __shared__ __align__(8) float2 exch[256];
  for (int i = tg; i < QL2A * 4 * 256; i += 512) {
    int q3 = i >> 10, g = (i >> 8) & 3, jj = i & 255;
    wlds[q3][g][jj] =
        *(const float4*)(wb + ((size_t)((QR2 + q3) * 4 + g) * 256 + jj) * 4);
  }
  if (tg < 256) hsd[0][tg] = 0.f;
  float c = 0.f;
  __syncthreads();

  for (int s = 0; s < len; ++s) {
    const int t = d ? (len - 1 - s) : s;
    const int rp = t * B_ + b;
    const size_t xb = (size_t)rp * 2048 + d * 1024 + (size_t)g0 * 256 + j;
    float xv0 = xg[xb];
    float xv1 = xg[xb + 256];
    float4 hv = *(const float4*)&hsd[s & 1][l * 4];

    float aA0 = 0.f, aA1 = 0.f, aB0 = 0.f, aB1 = 0.f;
#pragma unroll
    for (int q = 0; q < QR2; ++q) {
      float b0 = rlane(hv.x, q), b1 = rlane(hv.y, q);
      float b2 = rlane(hv.z, q), b3 = rlane(hv.w, q);
      aA0 += wA[q].x * b0 + wA[q].y * b1;  aA1 += wA[q].z * b2 + wA[q].w * b3;
      aB0 += wB[q].x * b0 + wB[q].y * b1;  aB1 += wB[q].z * b2 + wB[q].w * b3;
    }
#pragma unroll
    for (int q3 = 0; q3 < QL2A; ++q3) {
      int q = QR2 + q3;
      float b0 = rlane(hv.x, q), b1 = rlane(hv.y, q);
      float b2 = rlane(hv.z, q), b3 = rlane(hv.w, q);
      float4 wa = wlds[q3][g0][j], wbq = wlds[q3][g0 + 1][j];
      aA0 += wa.x * b0 + wa.y * b1;   aA1 += wa.z * b2 + wa.w * b3;
      aB0 += wbq.x * b0 + wbq.y * b1; aB1 += wbq.z * b2 + wbq.w * b3;
    }
#pragma unroll 2
    for (int qs = 0; qs < QS2A; ++qs) {
      int q = QR2 + QL2A + qs;
      float4 wa = *(const float4*)(wb + ((size_t)(q * 4 + g0) * 256 + j) * 4);
      float4 wbq = *(const float4*)(wb + ((size_t)(q * 4 + g0 + 1) * 256 + j) * 4);
      float b0 = rlane(hv.x, q), b1 = rlane(hv.y, q);
      float b2 = rlane(hv.z, q), b3 = rlane(hv.w, q);
      aA0 += wa.x * b0 + wa.y * b1;   aA1 += wa.z * b2 + wa.w * b3;
      aB0 += wbq.x * b0 + wbq.y * b1; aB1 += wbq.z * b2 + wbq.w * b3;
    }

    float aA = aA0 + aA1 + xv0;
    float aB = aB0 + aB1 + xv1;
    if (gp == 1) exch[j] = make_float2(aA, aB);
    __syncthreads();
    if (gp == 0) {
      float2 go = exch[j];
      float si = 1.f / (1.f + expf(-aA));
      float sf = 1.f / (1.f + expf(-aB));
      float so = 1.f / (1.f + expf(-go.y));
      c = sf * c + si * tanhf(go.x);
      float h = so * tanhf(c);
      hsd[(s + 1) & 1][j] = h;
      out[(size_t)rp * 512 + d * 256 + j] = h;
    }
    __syncthreads();
  }
  if (gp == 0)
    for (int t = len; t < T_; ++t)
      out[(size_t)(t * B_ + b) * 512 + d * 256 + j] = 0.f;
}

// ---------------- lo LSTM: verbatim R8 (proven 1963 us, absmax 0.0) ----------
__global__ __launch_bounds__(1024, 4) void lstm_rec_lo(
    const float* __restrict__ xg, const float* __restrict__ whhL,
    float* __restrict__ out, const int* __restrict__ lens) {
  const int wg = blockIdx.x, dir = wg & 1, b = wg >> 1;
  const int len = lens[b];
  const int tg = threadIdx.x;
  const int j = tg >> 2, gt = tg & 3;
  const int row = gt * 256 + j;

  float wres[KR_LO];
#pragma unroll
  for (int k = 0; k < KR_LO; ++k)
    wres[k] = whhL[(size_t)(dir * KR_LO + k) * 1024 + tg];

  __shared__ __align__(16) float4 wlds[KLQ_LO][1024];
  __shared__ __align__(16) float hsd[2][256];
#pragma unroll
  for (int q = 0; q < KLQ_LO; ++q)
    wlds[q][tg] = *(const float4*)&whhL[WLDS_OFF_LO + (size_t)((dir * KLQ_LO + q) * 1024 + tg) * 4];
  if (tg < 256) hsd[0][tg] = 0.f;
  float c = 0.f;
  __syncthreads();

  const float* sp = whhL + WSTR_OFF_LO + (size_t)dir * NQS_LO * 4096 + (size_t)tg * 4;
  const int lane = tg & 63, qb = lane & ~3;

  for (int s = 0; s < len; ++s) {
    const int t = dir ? (len - 1 - s) : s;
    const int rp = t * B_ + b;
    float xv = xg[(size_t)rp * 2048 + dir * 1024 + row];
    float4 hv = *(const float4*)&hsd[s & 1][lane * 4];

    float acc0 = 0.f, acc1 = 0.f;
#pragma unroll
    for (int q = 0; q < KR_LO / 4; ++q) {
      float b0 = rlane(hv.x, q), b1 = rlane(hv.y, q);
      float b2 = rlane(hv.z, q), b3 = rlane(hv.w, q);
      acc0 += wres[4 * q + 0] * b0 + wres[4 * q + 1] * b1;
      acc1 += wres[4 * q + 2] * b2 + wres[4 * q + 3] * b3;
    }
#pragma unroll
    for (int q3 = 0; q3 < KLQ_LO; ++q3) {
      int q = KR_LO / 4 + q3;
      float4 wl = wlds[q3][tg];
      float b0 = rlane(hv.x, q), b1 = rlane(hv.y, q);
      float b2 = rlane(hv.z, q), b3 = rlane(hv.w, q);
      acc0 += wl.x * b0 + wl.y * b1;
      acc1 += wl.z * b2 + wl.w * b3;
    }
#pragma unroll 5
    for (int qq = 0; qq < NQS_LO; ++qq) {
      int q = KR_LO / 4 + KLQ_LO + qq;
      float4 wv = *(const float4*)(sp + (size_t)qq * 4096);
      float b0 = rlane(hv.x, q), b1 = rlane(hv.y, q);
      float b2 = rlane(hv.z, q), b3 = rlane(hv.w, q);
      acc0 += wv.x * b0 + wv.y * b1;
      acc1 += wv.z * b2 + wv.w * b3;
    }

    float a = acc0 + acc1 + xv;
    float v1 = __shfl(a, qb | 1);
    float v2 = __shfl(a, qb | 2);
    float v3 = __shfl(a, qb | 3);
    if (gt == 0) {
      float si = 1.f / (1.f + expf(-a));
      float sf = 1.f / (1.f + expf(-v1));
      float so = 1.f / (1.f + expf(-v3));
      c = sf * c + si * tanhf(v2);
      float h = so * tanhf(c);
      hsd[(s + 1) & 1][j] = h;
      out[(size_t)rp * 512 + dir * 256 + j] = h;
    }
    __syncthreads();
  }
  for (int t = len; t < T_; ++t)
    if (gt == 0) out[(size_t)(t * B_ + b) * 512 + dir * 256 + j] = 0.f;
}

// ---------------- Viterbi (one wave per batch; ref fp-op order) ----------------
__global__ __launch_bounds__(64) void viterbi(
    const float* __restrict__ emis, const float* __restrict__ trans,
    const float* __restrict__ startv, const float* __restrict__ endv,
    const int* __restrict__ lens, int* __restrict__ outp) {
  int b = blockIdx.x, lane = threadIdx.x;
  __shared__ float tr[KTAG * KTAG];
  __shared__ float fin[KTAG];
  __shared__ unsigned char hist[T_ * KTAG];
  for (int i = lane; i < KTAG * KTAG; i += 64) tr[i] = trans[i];
  int len = lens[b];
  float score = (lane < KTAG) ? startv[lane] + emis[(size_t)b * 64 + lane] : -3e38f;
  __syncthreads();
  for (int t = 1; t < len; ++t) {
    float e = (lane < KTAG) ? emis[(size_t)(t * B_ + b) * 64 + lane] : 0.f;
    float best = -3e38f; int bp = 0;
    for (int p = 0; p < KTAG; ++p) {         // ascending p + strict '>': first-index
      float cand = (__shfl(score, p) + tr[p * KTAG + lane]) + e;  // ref op order
      if (cand > best) { best = cand; bp = p; }
    }
    if (lane < KTAG) { score = best; hist[t * KTAG + lane] = (unsigned char)bp; }
  }
  if (lane < KTAG) fin[lane] = score + endv[lane];
  __syncthreads();
  if (lane == 0) {
    float bb = -3e38f; int tag = 0;
    for (int p = 0; p < KTAG; ++p)
      if (fin[p] > bb) { bb = fin[p]; tag = p; }
    for (int t = len - 1; t >= 1; --t) {
      outp[t * B_ + b] = tag;
      tag = hist[t * KTAG + tag];
    }
    outp[b] = tag;
  }
  for (int t = len + lane; t < T_; t += 64) outp[t * B_ + b] = 0;
}

// ---------------- diagnostics (slim) ----------------
__global__ void sentinel_fill(int* __restrict__ outp, int val) {
  int i = blockIdx.x * 256 + threadIdx.x;
  if (i < TB_) outp[i] = val;
}
__global__ void diag_init(int* __restrict__ f) { if (threadIdx.x == 0) f[0] = 0; }
__global__ void check_nan(const float* __restrict__ p, long n, int* __restrict__ f) {
  long i0 = (long)blockIdx.x * 256 + threadIdx.x;
  int bad = 0;
  for (long i = i0; i < n; i += (long)gridDim.x * 256)
    if (!(fabsf(p[i]) <= 1e8f)) bad = 1;
  if (bad) atomicOr(&f[0], 1);
}
__global__ void verdict(const int* __restrict__ f, int* __restrict__ outp) {
  if (f[0]) outp[threadIdx.x] = -4096;
}

// ---------------- host ----------------

extern "C" void kernel_launch(void* const* d_in, const int* in_sizes, int n_in,
                              void* d_out, int out_size, void* d_ws, size_t ws_size,
                              hipStream_t stream) {
  int* outp = (int*)d_out;

  static const int exp_sizes[14] = {16384, 64, 15000000, 614400, 524288, 2048,
                                    1048576, 524288, 2048, 10240, 20, 400, 20, 20};
  int badi = (n_in == 14) ? -1 : 14;
  if (badi < 0)
    for (int i = 0; i < 14; ++i)
      if (in_sizes[i] != exp_sizes[i]) { badi = i; break; }
  if (badi >= 0) {
    hipLaunchKernelGGL(sentinel_fill, dim3((TB_ + 255) / 256), dim3(256), 0, stream,
                       outp, -(20000 + badi));
    return;
  }

  const int*   x      = (const int*)d_in[0];
  const int*   lens   = (const int*)d_in[1];
  const float* emb    = (const float*)d_in[2];
  const float* Wih0   = (const float*)d_in[3];
  const float* Whh0   = (const float*)d_in[4];
  const float* b0     = (const float*)d_in[5];
  const float* Wih1   = (const float*)d_in[6];
  const float* Whh1   = (const float*)d_in[7];
  const float* b1     = (const float*)d_in[8];
  const float* Wout   = (const float*)d_in[9];
  const float* bout   = (const float*)d_in[10];
  const float* trans  = (const float*)d_in[11];
  const float* startv = (const float*)d_in[12];
  const float* endv   = (const float*)d_in[13];

  // cascades gated on proof of residency (no scratch).
  static int chosen = -1, guse = -1;
  if (chosen < 0) {
    chosen = 0;
    hipFuncAttributes fa;
    if (hipFuncGetAttributes(&fa, reinterpret_cast<const void*>(&lstm_rec_hi2)) ==
            hipSuccess &&
        fa.localSizeBytes == 0 && fa.numRegs >= 150)
      chosen = 1;
    if (hipFuncGetAttributes(&fa, reinterpret_cast<const void*>(&lstm_rec_hi4c)) ==
            hipSuccess &&
        fa.localSizeBytes == 0 && fa.numRegs >= 130)
      chosen = 2;
    guse = 0;
    if (hipFuncGetAttributes(&fa, reinterpret_cast<const void*>(&gemm_mid)) ==
            hipSuccess &&
        fa.localSizeBytes == 0)
      guse = 1;
  }

  const size_t sz_whh = (size_t)524288 * 4;   // 2 MiB per layer per layout

  const size_t need =
      (size_t)TB_ * 2048 * 4      // xg
    + (size_t)TB_ * EPAD * 4     // xsA
    + (size_t)TB_ * 512 * 4      // outh
    + (size_t)2048 * EPAD * 4    // B0t
    + (size_t)64 * 512 * 4       // Bot
    + 4 * sz_whh                 // whh{0,1} x {U,L}
    + 64 * 4                     // biaso
    + (size_t)TB_ * 64 * 4       // emis
    + 64;                        // diag

  if (ws_size < need) {
    hipLaunchKernelGGL(sentinel_fill, dim3((TB_ + 255) / 256), dim3(256), 0, stream,
                       outp, -(int)(10000 + (ws_size >> 20)));
    return;
  }

  char* w = (char*)d_ws;
  float* xg    = (float*)w;  w += (size_t)TB_ * 2048 * 4;
  float* xsA   = (float*)w;  w += (size_t)TB_ * EPAD * 4;
  float* outh  = (float*)w;  w += (size_t)TB_ * 512 * 4;
  float* B0t   = (float*)w;  w += (size_t)2048 * EPAD * 4;
  float* Bot   = (float*)w;  w += (size_t)64 * 512 * 4;
  float* whh0U = (float*)w;  w += sz_whh;
  float* whh1U = (float*)w;  w += sz_whh;
  float* whh0L = (float*)w;  w += sz_whh;
  float* whh1L = (float*)w;  w += sz_whh;
  float* biaso = (float*)w;  w += 64 * 4;
  float* emis  = (float*)w;  w += (size_t)TB_ * 64 * 4;
  int*   diag  = (int*)w;    w += 64;

  hipLaunchKernelGGL(diag_init, dim3(1), dim3(64), 0, stream, diag);
  hipLaunchKernelGGL(prep_embed, dim3(TB_), dim3(64), 0, stream, x, emb, xsA);
  hipLaunchKernelGGL(prep_b0t, dim3((2048 * EPAD + 255) / 256), dim3(256), 0, stream, Wih0, B0t);
  hipLaunchKernelGGL(prep_bot64, dim3(128), dim3(256), 0, stream, Wout, Bot, bout, biaso);
  if (chosen >= 1) {
    hipLaunchKernelGGL(prep_whh4, dim3(2048), dim3(256), 0, stream, Whh0, whh0U);
    hipLaunchKernelGGL(prep_whh4, dim3(2048), dim3(256), 0, stream, Whh1, whh1U);
  } else {
    hipLaunchKernelGGL(prep_whh2, dim3(2048), dim3(256), 0, stream, Whh0, whh0L);
    hipLaunchKernelGGL(prep_whh2, dim3(2048), dim3(256), 0, stream, Whh1, whh1L);
  }

  // layer 0 input GEMM (M=16384, N=2048, K=304)
  if (guse)
    hipLaunchKernelGGL(gemm_mid, dim3(128 * 32), dim3(256), 0, stream,
                       xsA, EPAD, B0t, EPAD, xg, 2048, b0, 32, EPAD);
  else
    hipLaunchKernelGGL(gemm_f32, dim3(256 * 32), dim3(256), 0, stream,
                       xsA, EPAD, B0t, EPAD, xg, 2048, b0, 32, EPAD);
  if (chosen == 2)
    hipLaunchKernelGGL(lstm_rec_hi4c, dim3(128), dim3(512), 0, stream, xg, whh0U, outh, lens);
  else if (chosen == 1)
    hipLaunchKernelGGL(lstm_rec_hi2, dim3(128), dim3(512), 0, stream, xg, whh0U, outh, lens);
  else
    hipLaunchKernelGGL(lstm_rec_lo, dim3(128), dim3(1024), 0, stream, xg, whh0L, outh, lens);
  // layer 1 input GEMM (M=16384, N=2048, K=512)
  if (guse)
    hipLaunchKernelGGL(gemm_mid, dim3(128 * 32), dim3(256), 0, stream,
                       outh, 512, Wih1, 512, xg, 2048, b1, 32, 512);
  else
    hipLaunchKernelGGL(gemm_f32, dim3(256 * 32), dim3(256), 0, stream,
                       outh, 512, Wih1, 512, xg, 2048, b1, 32, 512);
  if (chosen == 2)
    hipLaunchKernelGGL(lstm_rec_hi4c, dim3(128), dim3(512), 0, stream, xg, whh1U, outh, lens);
  else if (chosen == 1)
    hipLaunchKernelGGL(lstm_rec_hi2, dim3(128), dim3(512), 0, stream, xg, whh1U, outh, lens);
  else
    hipLaunchKernelGGL(lstm_rec_lo, dim3(128), dim3(1024), 0, stream, xg, whh1L, outh, lens);
  // emissions (N padded to 64) + decode
  hipLaunchKernelGGL(gemm_f32, dim3(256), dim3(256), 0, stream,
                     outh, 512, Bot, 512, emis, 64, biaso, 1, 512);
  hipLaunchKernelGGL(check_nan, dim3(256), dim3(256), 0, stream,
                     emis, (long)TB_ * 64, diag);
  hipLaunchKernelGGL(viterbi, dim3(B_), dim3(64), 0, stream,
                     emis, trans, startv, endv, lens, outp);
  hipLaunchKernelGGL(verdict, dim3(1), dim3(64), 0, stream, diag, outp);
}

// Round 14
// 3923.516 us; speedup vs baseline: 1.0190x; 1.0017x over previous
//
#include <hip/hip_runtime.h>
#include <stdint.h>

// BiLSTM-CRF on gfx950 — fp32 (validated absmax 0.0). R20: spend risk only in
// PROVEN register-budget shapes. (1) gemm_wide: 512-thr WGs get a 128-reg
// default budget (R7 measured); 128x128 tile, 32 acc/thread = ~60 regs, deep
// inside it (gemm_mid/gemm128 failed on 256-thr 64-reg heuristics).
// 32 FMA : 3 LDS-b128 vs 16:2 -> big GEMMs ~650 -> ~480 us. k-ascending
// chain -> bitwise-same C. (2) lstm hi2b = hi2 + QL 8->9 ONLY (register-
// neutral LDS change; R17's failure isolated to unroll-4's +64 live regs).
// Cascades: hi2b -> hi2 -> lo ; gemm_wide -> gemm_f32. Fallbacks proven.

#define T_ 256
#define B_ 64
#define EPAD 304
#define KTAG 20
#define TB_ (T_ * B_)

// hi partitions (global k-quads 0..63, q ascending)
#define QR2 22                  // quads resident per gate-row (176 pinned, proven)
#define QL2A 8                  // hi2: quads in LDS (128 KiB)
#define QS2A 34                 // hi2: streamed
#define QL2B 9                  // hi2b: quads in LDS (144 KiB)
#define QS2B 33                 // hi2b: streamed

// lo (R8) partition
#define KR_LO 64
#define KLQ_LO 3
#define NQS_LO 45
#define WLDS_OFF_LO (2 * KR_LO * 1024)                    // 131072 floats
#define WSTR_OFF_LO (WLDS_OFF_LO + 2 * KLQ_LO * 1024 * 4) // 155648 floats

__device__ __forceinline__ float rlane(float v, int l) {
  return __int_as_float(__builtin_amdgcn_readlane(__float_as_int(v), l));
}

// ---------------- prep ----------------

__global__ void prep_embed(const int* __restrict__ x, const float* __restrict__ emb,
                           float* __restrict__ xsA) {
  int r = blockIdx.x;
  int tok = x[r];
  const float* src = emb + (size_t)tok * 300;
  for (int e = threadIdx.x; e < EPAD; e += 64)
    xsA[(size_t)r * EPAD + e] = (e < 300) ? src[e] : 0.f;
}

__global__ void prep_b0t(const float* __restrict__ Wih0, float* __restrict__ B0t) {
  int idx = blockIdx.x * 256 + threadIdx.x;
  if (idx >= 2048 * EPAD) return;
  int n = idx / EPAD, k = idx % EPAD;
  B0t[idx] = (k < 300) ? Wih0[(size_t)n * 300 + k] : 0.f;
}

__global__ void prep_bot64(const float* __restrict__ Wout, float* __restrict__ Bot,
                           const float* __restrict__ bout, float* __restrict__ biaso) {
  int idx = blockIdx.x * 256 + threadIdx.x;   // 64*512
  int n = idx >> 9, k = idx & 511;
  Bot[idx] = (n < KTAG) ? Wout[(size_t)n * 512 + k] : 0.f;
  if (idx < 64) biaso[idx] = (idx < KTAG) ? bout[idx] : 0.f;
}

// hi layout: whhU[d][q=k/4][gate][j][e]  (partition-agnostic full layout)
__global__ void prep_whh4(const float* __restrict__ Whh, float* __restrict__ whhU) {
  int idx = blockIdx.x * 256 + threadIdx.x;   // 524288
  int d = idx >> 18, rem = idx & 262143, row = rem >> 8, k = rem & 255;
  float v = Whh[(size_t)d * 262144 + (size_t)row * 256 + k];
  int gt = row >> 8, j = row & 255;
  int q = k >> 2, e = k & 3;
  whhU[((((size_t)d * 64 + q) * 4 + gt) * 256 + j) * 4 + e] = v;
}

// lo layout (R8): thread tg owns row (tg&3)*256 + (tg>>2)
__global__ void prep_whh2(const float* __restrict__ Whh, float* __restrict__ whhL) {
  int idx = blockIdx.x * 256 + threadIdx.x;   // 524288
  int d = idx >> 18, rem = idx & 262143, k = rem >> 10, tg = rem & 1023;
  int row = (tg & 3) * 256 + (tg >> 2);
  float v = Whh[(size_t)d * 262144 + (size_t)row * 256 + k];
  if (k < KR_LO) {
    whhL[(size_t)(d * KR_LO + k) * 1024 + tg] = v;
  } else if (k < KR_LO + 12) {
    int kk = k - KR_LO, q = kk >> 2, e = kk & 3;
    whhL[WLDS_OFF_LO + (size_t)((d * KLQ_LO + q) * 1024 + tg) * 4 + e] = v;
  } else {
    int kk = k - KR_LO - 12, q = kk >> 2, e = kk & 3;
    whhL[WSTR_OFF_LO + (size_t)((d * NQS_LO + q) * 1024 + tg) * 4 + e] = v;
  }
}

// ---------------- fp32 GEMM (64x64 tile, proven): C = A * Bt^T + bias -------
__global__ __launch_bounds__(256) void gemm_f32(
    const float* __restrict__ A, int lda, const float* __restrict__ Bt, int ldb,
    float* __restrict__ C, int ldc, const float* __restrict__ bias,
    int ntn, int K) {
  const int tm = blockIdx.x / ntn, tn = blockIdx.x % ntn;
  const int m0 = tm * 64, n0 = tn * 64;
  __shared__ __align__(16) float As[16][64];
  __shared__ __align__(16) float Bs[16][64];
  const int tid = threadIdx.x;
  const int mm = tid >> 2, kq = (tid & 3) * 4;
  const int tx = tid & 15, ty = tid >> 4;
  float acc[4][4] = {};
  for (int k0 = 0; k0 < K; k0 += 16) {
    float4 av = *(const float4*)&A[(size_t)(m0 + mm) * lda + k0 + kq];
    float4 bv = *(const float4*)&Bt[(size_t)(n0 + mm) * ldb + k0 + kq];
    __syncthreads();                       // guard prev-iter LDS reads
    As[kq + 0][mm] = av.x; As[kq + 1][mm] = av.y;
    As[kq + 2][mm] = av.z; As[kq + 3][mm] = av.w;
    Bs[kq + 0][mm] = bv.x; Bs[kq + 1][mm] = bv.y;
    Bs[kq + 2][mm] = bv.z; Bs[kq + 3][mm] = bv.w;
    __syncthreads();
#pragma unroll
    for (int kk = 0; kk < 16; ++kk) {
      float4 a4 = *(const float4*)&As[kk][ty * 4];
      float4 b4 = *(const float4*)&Bs[kk][tx * 4];
      acc[0][0] += a4.x * b4.x; acc[0][1] += a4.x * b4.y;
      acc[0][2] += a4.x * b4.z; acc[0][3] += a4.x * b4.w;
      acc[1][0] += a4.y * b4.x; acc[1][1] += a4.y * b4.y;
      acc[1][2] += a4.y * b4.z; acc[1][3] += a4.y * b4.w;
      acc[2][0] += a4.z * b4.x; acc[2][1] += a4.z * b4.y;
      acc[2][2] += a4.z * b4.z; acc[2][3] += a4.z * b4.w;
      acc[3][0] += a4.w * b4.x; acc[3][1] += a4.w * b4.y;
      acc[3][2] += a4.w * b4.z; acc[3][3] += a4.w * b4.w;
    }
  }
#pragma unroll
  for (int i = 0; i < 4; ++i)
#pragma unroll
    for (int j = 0; j < 4; ++j)
      C[(size_t)(m0 + ty * 4 + i) * ldc + n0 + tx * 4 + j] =
          acc[i][j] + bias[n0 + tx * 4 + j];
}

// ---------------- gemm_wide: 128x128 tile, BK=16, 512 thr, 4x8/thread -------
// 512-thr WG -> proven 128-reg default budget (R7). 32 acc + ~25 working
// regs, deep inside it. 32 FMA : 3 LDS-b128 per kk. Per-output k-chain
// ascending -> bitwise-same C as gemm_f32. Requires M%128==0, N%128==0,
// K%16==0 (true for both big GEMMs).
__global__ __launch_bounds__(512) void gemm_wide(
    const float* __restrict__ A, int lda, const float* __restrict__ Bt, int ldb,
    float* __restrict__ C, int ldc, const float* __restrict__ bias,
    int ntn, int K) {
  const int tm = blockIdx.x / ntn, tn = blockIdx.x % ntn;
  const int m0 = tm * 128, n0 = tn * 128;
  __shared__ __align__(16) float As[16][128];   // 8 KiB
  __shared__ __align__(16) float Bs[16][128];   // 8 KiB
  const int tid = threadIdx.x;
  const int lrow = tid >> 2, lkq = (tid & 3) * 4;   // loader: 1 float4 each
  const int tx = tid & 15, ty = tid >> 4;           // 16 col-grp, 32 row-grp
  float acc[4][8] = {};
  for (int k0 = 0; k0 < K; k0 += 16) {
    float4 av = *(const float4*)&A[(size_t)(m0 + lrow) * lda + k0 + lkq];
    float4 bv = *(const float4*)&Bt[(size_t)(n0 + lrow) * ldb + k0 + lkq];
    __syncthreads();                       // guard prev-iter LDS reads
    As[lkq + 0][lrow] = av.x; As[lkq + 1][lrow] = av.y;
    As[lkq + 2][lrow] = av.z; As[lkq + 3][lrow] = av.w;
    Bs[lkq + 0][lrow] = bv.x; Bs[lkq + 1][lrow] = bv.y;
    Bs[lkq + 2][lrow] = bv.z; Bs[lkq + 3][lrow] = bv.w;
    __syncthreads();
#pragma unroll
    for (int kk = 0; kk < 16; ++kk) {
      float4 a4 = *(const float4*)&As[kk][ty * 4];
      float4 b0 = *(const float4*)&Bs[kk][tx * 8];
      float4 b1 = *(const float4*)&Bs[kk][tx * 8 + 4];
      acc[0][0] += a4.x * b0.x; acc[0][1] += a4.x * b0.y;
      acc[0][2] += a4.x * b0.z; acc[0][3] += a4.x * b0.w;
      acc[0][4] += a4.x * b1.x; acc[0][5] += a4.x * b1.y;
      acc[0][6] += a4.x * b1.z; acc[0][7] += a4.x * b1.w;
      acc[1][0] += a4.y * b0.x; acc[1][1] += a4.y * b0.y;
      acc[1][2] += a4.y * b0.z; acc[1][3] += a4.y * b0.w;
      acc[1][4] += a4.y * b1.x; acc[1][5] += a4.y * b1.y;
      acc[1][6] += a4.y * b1.z; acc[1][7] += a4.y * b1.w;
      acc[2][0] += a4.z * b0.x; acc[2][1] += a4.z * b0.y;
      acc[2][2] += a4.z * b0.z; acc[2][3] += a4.z * b0.w;
      acc[2][4] += a4.z * b1.x; acc[2][5] += a4.z * b1.y;
      acc[2][6] += a4.z * b1.z; acc[2][7] += a4.z * b1.w;
      acc[3][0] += a4.w * b0.x; acc[3][1] += a4.w * b0.y;
      acc[3][2] += a4.w * b0.z; acc[3][3] += a4.w * b0.w;
      acc[3][4] += a4.w * b1.x; acc[3][5] += a4.w * b1.y;
      acc[3][6] += a4.w * b1.z; acc[3][7] += a4.w * b1.w;
    }
  }
#pragma unroll
  for (int i = 0; i < 4; ++i)
#pragma unroll
    for (int j = 0; j < 8; ++j)
      C[(size_t)(m0 + ty * 4 + i) * ldc + n0 + tx * 8 + j] =
          acc[i][j] + bias[n0 + tx * 8 + j];
}

// ---------------- hi2b LSTM: hi2 + QL=9 (register-neutral) ----------
__global__ __attribute__((amdgpu_flat_work_group_size(512, 512),
                          amdgpu_waves_per_eu(2, 2)))
void lstm_rec_hi2b(const float* __restrict__ xg, const float* __restrict__ whhU,
                   float* __restrict__ out, const int* __restrict__ lens) {
  const int wg = blockIdx.x, d = wg & 1, b = wg >> 1;
  const int len = lens[b];
  const int tg = threadIdx.x;
  const int j = tg & 255, gp = tg >> 8;    // gp 0: gates i,f ; gp 1: gates g,o
  const int g0 = gp * 2;
  const int l = tg & 63;
  const float* wb = whhU + (size_t)d * 64 * 4096;

  float4 wA[QR2], wB[QR2];
#pragma unroll
  for (int q = 0; q < QR2; ++q) {
    wA[q] = *(const float4*)(wb + ((size_t)(q * 4 + g0) * 256 + j) * 4);
    wB[q] = *(const float4*)(wb + ((size_t)(q * 4 + g0 + 1) * 256 + j) * 4);
  }
#pragma unroll
  for (int q = 0; q < QR2; ++q) {
    asm volatile("" : "+v"(wA[q].x), "+v"(wA[q].y), "+v"(wA[q].z), "+v"(wA[q].w));
    asm volatile("" : "+v"(wB[q].x), "+v"(wB[q].y), "+v"(wB[q].z), "+v"(wB[q].w));
  }

  __shared__ __align__(16) float4 wlds[QL2B][4][256];  // 144 KiB
  __shared__ __align__(16) float hsd[2][256];
  __shared__ __align__(8) float2 exch[256];
  for (int i = tg; i < QL2B * 4 * 256; i += 512) {
    int q3 = i >> 10, g = (i >> 8) & 3, jj = i & 255;
    wlds[q3][g][jj] =
        *(const float4*)(wb + ((size_t)((QR2 + q3) * 4 + g) * 256 + jj) * 4);
  }
  if (tg < 256) hsd[0][tg] = 0.f;
  float c = 0.f;
  __syncthreads();

  for (int s = 0; s < len; ++s) {
    const int t = d ? (len - 1 - s) : s;
    const int rp = t * B_ + b;
    const size_t xb = (size_t)rp * 2048 + d * 1024 + (size_t)g0 * 256 + j;
    float xv0 = xg[xb];
    float xv1 = xg[xb + 256];
    float4 hv = *(const float4*)&hsd[s & 1][l * 4];

    float aA0 = 0.f, aA1 = 0.f, aB0 = 0.f, aB1 = 0.f;
#pragma unroll
    for (int q = 0; q < QR2; ++q) {        // k ascending = validated FP chain
      float b0 = rlane(hv.x, q), b1 = rlane(hv.y, q);
      float b2 = rlane(hv.z, q), b3 = rlane(hv.w, q);
      aA0 += wA[q].x * b0 + wA[q].y * b1;  aA1 += wA[q].z * b2 + wA[q].w * b3;
      aB0 += wB[q].x * b0 + wB[q].y * b1;  aB1 += wB[q].z * b2 + wB[q].w * b3;
    }
#pragma unroll
    for (int q3 = 0; q3 < QL2B; ++q3) {
      int q = QR2 + q3;
      float b0 = rlane(hv.x, q), b1 = rlane(hv.y, q);
      float b2 = rlane(hv.z, q), b3 = rlane(hv.w, q);
      float4 wa = wlds[q3][g0][j], wbq = wlds[q3][g0 + 1][j];
      aA0 += wa.x * b0 + wa.y * b1;   aA1 += wa.z * b2 + wa.w * b3;
      aB0 += wbq.x * b0 + wbq.y * b1; aB1 += wbq.z * b2 + wbq.w * b3;
    }
#pragma unroll 2
    for (int qs = 0; qs < QS2B; ++qs) {
      int q = QR2 + QL2B + qs;
      float4 wa = *(const float4*)(wb + ((size_t)(q * 4 + g0) * 256 + j) * 4);
      float4 wbq = *(const float4*)(wb + ((size_t)(q * 4 + g0 + 1) * 256 + j) * 4);
      float b0 = rlane(hv.x, q), b1 = rlane(hv.y, q);
      float b2 = rlane(hv.z, q), b3 = rlane(hv.w, q);
      aA0 += wa.x * b0 + wa.y * b1;   aA1 += wa.z * b2 + wa.w * b3;
      aB0 += wbq.x * b0 + wbq.y * b1; aB1 += wbq.z * b2 + wbq.w * b3;
    }

    float aA = aA0 + aA1 + xv0;            // gp0: i ; gp1: g
    float aB = aB0 + aB1 + xv1;            // gp0: f ; gp1: o
    if (gp == 1) exch[j] = make_float2(aA, aB);
    __syncthreads();
    if (gp == 0) {
      float2 go = exch[j];
      float si = 1.f / (1.f + expf(-aA));  // i
      float sf = 1.f / (1.f + expf(-aB));  // f
      float so = 1.f / (1.f + expf(-go.y));// o
      c = sf * c + si * tanhf(go.x);       // g
      float h = so * tanhf(c);
      hsd[(s + 1) & 1][j] = h;
      out[(size_t)rp * 512 + d * 256 + j] = h;
    }
    __syncthreads();
  }
  if (gp == 0)                              // pack_padded: padded outputs zero
    for (int t = len; t < T_; ++t)
      out[(size_t)(t * B_ + b) * 512 + d * 256 + j] = 0.f;
}

// ---------------- hi2 LSTM: R13 verbatim (proven 1543-1571 us) ----------
__global__ __attribute__((amdgpu_flat_work_group_size(512, 512),
                          amdgpu_waves_per_eu(2, 2)))
void lstm_rec_hi2(const float* __restrict__ xg, const float* __restrict__ whhU,
                  float* __restrict__ out, const int* __restrict__ lens) {
  const int wg = blockIdx.x, d = wg & 1, b = wg >> 1;
  const int len = lens[b];
  const int tg = threadIdx.x;
  const int j = tg & 255, gp = tg >> 8;
  const int g0 = gp * 2;
  const int l = tg & 63;
  const float* wb = whhU + (size_t)d * 64 * 4096;

  float4 wA[QR2], wB[QR2];
#pragma unroll
  for (int q = 0; q < QR2; ++q) {
    wA[q] = *(const float4*)(wb + ((size_t)(q * 4 + g0) * 256 + j) * 4);
    wB[q] = *(const float4*)(wb + ((size_t)(q * 4 + g0 + 1) * 256 + j) * 4);
  }
#pragma unroll
  for (int q = 0; q < QR2; ++q) {
    asm volatile("" : "+v"(wA[q].x), "+v"(wA[q].y), "+v"(wA[q].z), "+v"(wA[q].w));
    asm volatile("" : "+v"(wB[q].x), "+v"(wB[q].y), "+v"(wB[q].z), "+v"(wB[q].w));
  }

  __shared__ __align__(16) float4 wlds[QL2A][4][256];  // 128 KiB
  __shared__ __align__(16) float hsd[2][256];
  __shared__ __align__(8) float2 exch[256];
  for (int i = tg; i < QL2A * 4 * 256; i += 512) {
    int q3 = i >> 10, g = (i >> 8) & 3, jj = i & 255;
    wlds[q3][g][jj] =
        *(const float4*)(wb + ((size_t)((QR2 + q3) * 4 + g) * 256 + jj) * 4);
  }
  if (tg < 256) hsd[0][tg] = 0.f;
  float c = 0.f;
  __syncthreads();

  for (int s = 0; s < len; ++s) {
    const int t = d ? (len - 1 - s) : s;
    const int rp = t * B_ + b;
    const size_t xb = (size_t)rp * 2048 + d * 1024 + (size_t)g0 * 256 + j;
    float xv0 = xg[xb];
    float xv1 = xg[xb + 256];
    float4 hv = *(const float4*)&hsd[s & 1][l * 4];

    float aA0 = 0.f, aA1 = 0.f, aB0 = 0.f, aB1 = 0.f;
#pragma unroll
    for (int q = 0; q < QR2; ++q) {
      float b0 = rlane(hv.x, q), b1 = rlane(hv.y, q);
      float b2 = rlane(hv.z, q), b3 = rlane(hv.w, q);
      aA0 += wA[q].x * b0 + wA[q].y * b1;  aA1 += wA[q].z * b2 + wA[q].w * b3;
      aB0 += wB[q].x * b0 + wB[q].y * b1;  aB1 += wB[q].z * b2 + wB[q].w * b3;
    }
#pragma unroll
    for (int q3 = 0; q3 < QL2A; ++q3) {
      int q = QR2 + q3;
      float b0 = rlane(hv.x, q), b1 = rlane(hv.y, q);
      float b2 = rlane(hv.z, q), b3 = rlane(hv.w, q);
      float4 wa = wlds[q3][g0][j], wbq = wlds[q3][g0 + 1][j];
      aA0 += wa.x * b0 + wa.y * b1;   aA1 += wa.z * b2 + wa.w * b3;
      aB0 += wbq.x * b0 + wbq.y * b1; aB1 += wbq.z * b2 + wbq.w * b3;
    }
#pragma unroll 2
    for (int qs = 0; qs < QS2A; ++qs) {
      int q = QR2 + QL2A + qs;
      float4 wa = *(const float4*)(wb + ((size_t)(q * 4 + g0) * 256 + j) * 4);
      float4 wbq = *(const float4*)(wb + ((size_t)(q * 4 + g0 + 1) * 256 + j) * 4);
      float b0 = rlane(hv.x, q), b1 = rlane(hv.y, q);
      float b2 = rlane(hv.z, q), b3 = rlane(hv.w, q);
      aA0 += wa.x * b0 + wa.y * b1;   aA1 += wa.z * b2 + wa.w * b3;
      aB0 += wbq.x * b0 + wbq.y * b1; aB1 += wbq.z * b2 + wbq.w * b3;
    }

    float aA = aA0 + aA1 + xv0;
    float aB = aB0 + aB1 + xv1;
    if (gp == 1) exch[j] = make_float2(aA, aB);
    __syncthreads();
    if (gp == 0) {
      float2 go = exch[j];
      float si = 1.f / (1.f + expf(-aA));
      float sf = 1.f / (1.f + expf(-aB));
      float so = 1.f / (1.f + expf(-go.y));
      c = sf * c + si * tanhf(go.x);
      float h = so * tanhf(c);
      hsd[(s + 1) & 1][j] = h;
      out[(size_t)rp * 512 + d * 256 + j] = h;
    }
    __syncthreads();
  }
  if (gp == 0)
    for (int t = len; t < T_; ++t)
      out[(size_t)(t * B_ + b) * 512 + d * 256 + j] = 0.f;
}

// ---------------- lo LSTM: verbatim R8 (proven 1963 us, absmax 0.0) ----------
__global__ __launch_bounds__(1024, 4) void lstm_rec_lo(
    const float* __restrict__ xg, const float* __restrict__ whhL,
    float* __restrict__ out, const int* __restrict__ lens) {
  const int wg = blockIdx.x, dir = wg & 1, b = wg >> 1;
  const int len = lens[b];
  const int tg = threadIdx.x;
  const int j = tg >> 2, gt = tg & 3;
  const int row = gt * 256 + j;

  float wres[KR_LO];
#pragma unroll
  for (int k = 0; k < KR_LO; ++k)
    wres[k] = whhL[(size_t)(dir * KR_LO + k) * 1024 + tg];

  __shared__ __align__(16) float4 wlds[KLQ_LO][1024];
  __shared__ __align__(16) float hsd[2][256];
#pragma unroll
  for (int q = 0; q < KLQ_LO; ++q)
    wlds[q][tg] = *(const float4*)&whhL[WLDS_OFF_LO + (size_t)((dir * KLQ_LO + q) * 1024 + tg) * 4];
  if (tg < 256) hsd[0][tg] = 0.f;
  float c = 0.f;
  __syncthreads();

  const float* sp = whhL + WSTR_OFF_LO + (size_t)dir * NQS_LO * 4096 + (size_t)tg * 4;
  const int lane = tg & 63, qb = lane & ~3;

  for (int s = 0; s < len; ++s) {
    const int t = dir ? (len - 1 - s) : s;
    const int rp = t * B_ + b;
    float xv = xg[(size_t)rp * 2048 + dir * 1024 + row];
    float4 hv = *(const float4*)&hsd[s & 1][lane * 4];

    float acc0 = 0.f, acc1 = 0.f;
#pragma unroll
    for (int q = 0; q < KR_LO / 4; ++q) {
      float b0 = rlane(hv.x, q), b1 = rlane(hv.y, q);
      float b2 = rlane(hv.z, q), b3 = rlane(hv.w, q);
      acc0 += wres[4 * q + 0] * b0 + wres[4 * q + 1] * b1;
      acc1 += wres[4 * q + 2] * b2 + wres[4 * q + 3] * b3;
    }
#pragma unroll
    for (int q3 = 0; q3 < KLQ_LO; ++q3) {
      int q = KR_LO / 4 + q3;
      float4 wl = wlds[q3][tg];
      float b0 = rlane(hv.x, q), b1 = rlane(hv.y, q);
      float b2 = rlane(hv.z, q), b3 = rlane(hv.w, q);
      acc0 += wl.x * b0 + wl.y * b1;
      acc1 += wl.z * b2 + wl.w * b3;
    }
#pragma unroll 5
    for (int qq = 0; qq < NQS_LO; ++qq) {
      int q = KR_LO / 4 + KLQ_LO + qq;
      float4 wv = *(const float4*)(sp + (size_t)qq * 4096);
      float b0 = rlane(hv.x, q), b1 = rlane(hv.y, q);
      float b2 = rlane(hv.z, q), b3 = rlane(hv.w, q);
      acc0 += wv.x * b0 + wv.y * b1;
      acc1 += wv.z * b2 + wv.w * b3;
    }

    float a = acc0 + acc1 + xv;
    float v1 = __shfl(a, qb | 1);
    float v2 = __shfl(a, qb | 2);
    float v3 = __shfl(a, qb | 3);
    if (gt == 0) {
      float si = 1.f / (1.f + expf(-a));
      float sf = 1.f / (1.f + expf(-v1));
      float so = 1.f / (1.f + expf(-v3));
      c = sf * c + si * tanhf(v2);
      float h = so * tanhf(c);
      hsd[(s + 1) & 1][j] = h;
      out[(size_t)rp * 512 + dir * 256 + j] = h;
    }
    __syncthreads();
  }
  for (int t = len; t < T_; ++t)
    if (gt == 0) out[(size_t)(t * B_ + b) * 512 + dir * 256 + j] = 0.f;
}

// ---------------- Viterbi (one wave per batch; ref fp-op order) ----------------
__global__ __launch_bounds__(64) void viterbi(
    const float* __restrict__ emis, const float* __restrict__ trans,
    const float* __restrict__ startv, const float* __restrict__ endv,
    const int* __restrict__ lens, int* __restrict__ outp) {
  int b = blockIdx.x, lane = threadIdx.x;
  __shared__ float tr[KTAG * KTAG];
  __shared__ float fin[KTAG];
  __shared__ unsigned char hist[T_ * KTAG];
  for (int i = lane; i < KTAG * KTAG; i += 64) tr[i] = trans[i];
  int len = lens[b];
  float score = (lane < KTAG) ? startv[lane] + emis[(size_t)b * 64 + lane] : -3e38f;
  __syncthreads();
  for (int t = 1; t < len; ++t) {
    float e = (lane < KTAG) ? emis[(size_t)(t * B_ + b) * 64 + lane] : 0.f;
    float best = -3e38f; int bp = 0;
    for (int p = 0; p < KTAG; ++p) {         // ascending p + strict '>': first-index
      float cand = (__shfl(score, p) + tr[p * KTAG + lane]) + e;  // ref op order
      if (cand > best) { best = cand; bp = p; }
    }
    if (lane < KTAG) { score = best; hist[t * KTAG + lane] = (unsigned char)bp; }
  }
  if (lane < KTAG) fin[lane] = score + endv[lane];
  __syncthreads();
  if (lane == 0) {
    float bb = -3e38f; int tag = 0;
    for (int p = 0; p < KTAG; ++p)
      if (fin[p] > bb) { bb = fin[p]; tag = p; }
    for (int t = len - 1; t >= 1; --t) {
      outp[t * B_ + b] = tag;
      tag = hist[t * KTAG + tag];
    }
    outp[b] = tag;
  }
  for (int t = len + lane; t < T_; t += 64) outp[t * B_ + b] = 0;
}

// ---------------- diagnostics (slim) ----------------
__global__ void sentinel_fill(int* __restrict__ outp, int val) {
  int i = blockIdx.x * 256 + threadIdx.x;
  if (i < TB_) outp[i] = val;
}
__global__ void diag_init(int* __restrict__ f) { if (threadIdx.x == 0) f[0] = 0; }
__global__ void check_nan(const float* __restrict__ p, long n, int* __restrict__ f) {
  long i0 = (long)blockIdx.x * 256 + threadIdx.x;
  int bad = 0;
  for (long i = i0; i < n; i += (long)gridDim.x * 256)
    if (!(fabsf(p[i]) <= 1e8f)) bad = 1;
  if (bad) atomicOr(&f[0], 1);
}
__global__ void verdict(const int* __restrict__ f, int* __restrict__ outp) {
  if (f[0]) outp[threadIdx.x] = -4096;
}

// ---------------- host ----------------

extern "C" void kernel_launch(void* const* d_in, const int* in_sizes, int n_in,
                              void* d_out, int out_size, void* d_ws, size_t ws_size,
                              hipStream_t stream) {
  int* outp = (int*)d_out;

  static const int exp_sizes[14] = {16384, 64, 15000000, 614400, 524288, 2048,
                                    1048576, 524288, 2048, 10240, 20, 400, 20, 20};
  int badi = (n_in == 14) ? -1 : 14;
  if (badi < 0)
    for (int i = 0; i < 14; ++i)
      if (in_sizes[i] != exp_sizes[i]) { badi = i; break; }
  if (badi >= 0) {
    hipLaunchKernelGGL(sentinel_fill, dim3((TB_ + 255) / 256), dim3(256), 0, stream,
                       outp, -(20000 + badi));
    return;
  }

  const int*   x      = (const int*)d_in[0];
  const int*   lens   = (const int*)d_in[1];
  const float* emb    = (const float*)d_in[2];
  const float* Wih0   = (const float*)d_in[3];
  const float* Whh0   = (const float*)d_in[4];
  const float* b0     = (const float*)d_in[5];
  const float* Wih1   = (const float*)d_in[6];
  const float* Whh1   = (const float*)d_in[7];
  const float* b1     = (const float*)d_in[8];
  const float* Wout   = (const float*)d_in[9];
  const float* bout   = (const float*)d_in[10];
  const float* trans  = (const float*)d_in[11];
  const float* startv = (const float*)d_in[12];
  const float* endv   = (const float*)d_in[13];

  // cascades gated on proof of residency (no scratch).
  static int chosen = -1, guse = -1;
  if (chosen < 0) {
    chosen = 0;
    hipFuncAttributes fa;
    if (hipFuncGetAttributes(&fa, reinterpret_cast<const void*>(&lstm_rec_hi2)) ==
            hipSuccess &&
        fa.localSizeBytes == 0 && fa.numRegs >= 150)
      chosen = 1;
    if (hipFuncGetAttributes(&fa, reinterpret_cast<const void*>(&lstm_rec_hi2b)) ==
            hipSuccess &&
        fa.localSizeBytes == 0 && fa.numRegs >= 150)
      chosen = 2;
    guse = 0;
    if (hipFuncGetAttributes(&fa, reinterpret_cast<const void*>(&gemm_wide)) ==
            hipSuccess &&
        fa.localSizeBytes == 0)
      guse = 1;
  }

  const size_t sz_whh = (size_t)524288 * 4;   // 2 MiB per layer per layout

  const size_t need =
      (size_t)TB_ * 2048 * 4      // xg
    + (size_t)TB_ * EPAD * 4     // xsA
    + (size_t)TB_ * 512 * 4      // outh
    + (size_t)2048 * EPAD * 4    // B0t
    + (size_t)64 * 512 * 4       // Bot
    + 4 * sz_whh                 // whh{0,1} x {U,L}
    + 64 * 4                     // biaso
    + (size_t)TB_ * 64 * 4       // emis
    + 64;                        // diag

  if (ws_size < need) {
    hipLaunchKernelGGL(sentinel_fill, dim3((TB_ + 255) / 256), dim3(256), 0, stream,
                       outp, -(int)(10000 + (ws_size >> 20)));
    return;
  }

  char* w = (char*)d_ws;
  float* xg    = (float*)w;  w += (size_t)TB_ * 2048 * 4;
  float* xsA   = (float*)w;  w += (size_t)TB_ * EPAD * 4;
  float* outh  = (float*)w;  w += (size_t)TB_ * 512 * 4;
  float* B0t   = (float*)w;  w += (size_t)2048 * EPAD * 4;
  float* Bot   = (float*)w;  w += (size_t)64 * 512 * 4;
  float* whh0U = (float*)w;  w += sz_whh;
  float* whh1U = (float*)w;  w += sz_whh;
  float* whh0L = (float*)w;  w += sz_whh;
  float* whh1L = (float*)w;  w += sz_whh;
  float* biaso = (float*)w;  w += 64 * 4;
  float* emis  = (float*)w;  w += (size_t)TB_ * 64 * 4;
  int*   diag  = (int*)w;    w += 64;

  hipLaunchKernelGGL(diag_init, dim3(1), dim3(64), 0, stream, diag);
  hipLaunchKernelGGL(prep_embed, dim3(TB_), dim3(64), 0, stream, x, emb, xsA);
  hipLaunchKernelGGL(prep_b0t, dim3((2048 * EPAD + 255) / 256), dim3(256), 0, stream, Wih0, B0t);
  hipLaunchKernelGGL(prep_bot64, dim3(128), dim3(256), 0, stream, Wout, Bot, bout, biaso);
  if (chosen >= 1) {
    hipLaunchKernelGGL(prep_whh4, dim3(2048), dim3(256), 0, stream, Whh0, whh0U);
    hipLaunchKernelGGL(prep_whh4, dim3(2048), dim3(256), 0, stream, Whh1, whh1U);
  } else {
    hipLaunchKernelGGL(prep_whh2, dim3(2048), dim3(256), 0, stream, Whh0, whh0L);
    hipLaunchKernelGGL(prep_whh2, dim3(2048), dim3(256), 0, stream, Whh1, whh1L);
  }

  // layer 0 input GEMM (M=16384, N=2048, K=304)
  if (guse)
    hipLaunchKernelGGL(gemm_wide, dim3(128 * 16), dim3(512), 0, stream,
                       xsA, EPAD, B0t, EPAD, xg, 2048, b0, 16, EPAD);
  else
    hipLaunchKernelGGL(gemm_f32, dim3(256 * 32), dim3(256), 0, stream,
                       xsA, EPAD, B0t, EPAD, xg, 2048, b0, 32, EPAD);
  if (chosen == 2)
    hipLaunchKernelGGL(lstm_rec_hi2b, dim3(128), dim3(512), 0, stream, xg, whh0U, outh, lens);
  else if (chosen == 1)
    hipLaunchKernelGGL(lstm_rec_hi2, dim3(128), dim3(512), 0, stream, xg, whh0U, outh, lens);
  else
    hipLaunchKernelGGL(lstm_rec_lo, dim3(128), dim3(1024), 0, stream, xg, whh0L, outh, lens);
  // layer 1 input GEMM (M=16384, N=2048, K=512)
  if (guse)
    hipLaunchKernelGGL(gemm_wide, dim3(128 * 16), dim3(512), 0, stream,
                       outh, 512, Wih1, 512, xg, 2048, b1, 16, 512);
  else
    hipLaunchKernelGGL(gemm_f32, dim3(256 * 32), dim3(256), 0, stream,
                       outh, 512, Wih1, 512, xg, 2048, b1, 32, 512);
  if (chosen == 2)
    hipLaunchKernelGGL(lstm_rec_hi2b, dim3(128), dim3(512), 0, stream, xg, whh1U, outh, lens);
  else if (chosen == 1)
    hipLaunchKernelGGL(lstm_rec_hi2, dim3(128), dim3(512), 0, stream, xg, whh1U, outh, lens);
  else
    hipLaunchKernelGGL(lstm_rec_lo, dim3(128), dim3(1024), 0, stream, xg, whh1L, outh, lens);
  // emissions (N padded to 64) + decode
  hipLaunchKernelGGL(gemm_f32, dim3(256), dim3(256), 0, stream,
                     outh, 512, Bot, 512, emis, 64, biaso, 1, 512);
  hipLaunchKernelGGL(check_nan, dim3(256), dim3(256), 0, stream,
                     emis, (long)TB_ * 64, diag);
  hipLaunchKernelGGL(viterbi, dim3(B_), dim3(64), 0, stream,
                     emis, trans, startv, endv, lens, outp);
  hipLaunchKernelGGL(verdict, dim3(1), dim3(64), 0, stream, diag, outp);
}